// Round 4
// baseline (419.023 us; speedup 1.0000x reference)
//
#include <hip/hip_runtime.h>

#define N_NODES 100000
#define N_EDGES 1600000
#define IN_F    128
#define NEG_SLOPE 0.2f
#define NBUCK   512                 // bucket = dst>>8; 391 active
#define BCAP    5120                // padded bucket capacity (mean 4096, +16 sigma)
#define PCHUNK  4096                // edges per partition block
#define PGRID   391                 // ceil(N_EDGES / PCHUNK)
#define GEMMGRID 1563               // ceil(N_NODES / 64)
#define AGGBLKS 2048                // persistent agg grid: 8 blocks/CU x 256 CU

typedef __attribute__((ext_vector_type(8))) short bf16x8;
typedef __attribute__((ext_vector_type(4))) float f32x4;

__device__ __forceinline__ float bf2f(unsigned short u) {
    return __uint_as_float(((unsigned int)u) << 16);
}

// f32 -> bf16 round-to-nearest-even
__device__ __forceinline__ unsigned short f2bf(float f) {
    unsigned int u = __float_as_uint(f);
    u += 0x7FFFu + ((u >> 16) & 1u);
    return (unsigned short)(u >> 16);
}

// uniform-base + 32-bit-offset load: encourages global_load saddr form
__device__ __forceinline__ unsigned int ld_u32(const char* base, unsigned int off) {
    return *(const unsigned int*)(base + off);
}

// ---------------------------------------------------------------------------
// K1: cursor init (blocks 0..1) + weight pack (blocks 2..161).
// Pack layout: Wp[((nt*4+kt)*64+lane)*8+j] = W[kt*32+(lane>>4)*8+j][nt*16+(lane&15)]
// ---------------------------------------------------------------------------
__global__ __launch_bounds__(256) void init_pack(int* __restrict__ bcursor,
                                                 const float* __restrict__ W0,
                                                 const float* __restrict__ W1,
                                                 const float* __restrict__ W2,
                                                 const float* __restrict__ rW2,
                                                 unsigned short* __restrict__ W0p,
                                                 unsigned short* __restrict__ W1p,
                                                 unsigned short* __restrict__ W2p) {
    const int t = threadIdx.x;
    if (blockIdx.x < 2) {
        int i = blockIdx.x * 256 + t;
        if (i < NBUCK) bcursor[i] = i * BCAP;
        return;
    }
    int gid = (blockIdx.x - 2) * 256 + t;            // < 40960
    const float* W;
    unsigned short* Wp;
    int idx, ncols;
    if (gid < 16384)      { W = W0; Wp = W0p; idx = gid;          ncols = 128; }
    else if (gid < 32768) { W = W1; Wp = W1p; idx = gid - 16384;  ncols = 128; }
    else                  { W = W2; Wp = W2p; idx = gid - 32768;  ncols = 32;  }
    int j  = idx & 7;
    int l  = (idx >> 3) & 63;
    int kt = (idx >> 9) & 3;
    int nt = idx >> 11;
    int k  = kt * 32 + (l >> 4) * 8 + j;
    int n  = nt * 16 + (l & 15);
    float v;
    if (ncols == 128) v = W[k * 128 + n];
    else              v = (n < 16) ? W[k * 16 + n] : rW2[k * 16 + (n - 16)];
    Wp[idx] = f2bf(v);
}

// ---------------------------------------------------------------------------
// K2: edge partition into padded buckets (blocks [0,PGRID)) + layer-0 MFMA
// GEMM (blocks [PGRID, PGRID+GEMMGRID)).
// ---------------------------------------------------------------------------
__global__ __launch_bounds__(256) void part_gemm0(const int* __restrict__ src,
                                                  const int* __restrict__ dst,
                                                  int* __restrict__ bcursor,
                                                  unsigned int* __restrict__ pe, int nE,
                                                  const float* __restrict__ A,
                                                  const unsigned short* __restrict__ Wp,
                                                  const float* __restrict__ al,
                                                  const float* __restrict__ ar,
                                                  unsigned short* __restrict__ featb,
                                                  float* __restrict__ el,
                                                  float* __restrict__ er,
                                                  int nrows) {
    __shared__ int hist[NBUCK];
    __shared__ int lstart[NBUCK];
    __shared__ int gbase[NBUCK];
    __shared__ int curB[NBUCK];
    __shared__ int s[NBUCK];
    __shared__ unsigned int reorder[PCHUNK];

    const int t = threadIdx.x;

    if (blockIdx.x < PGRID) {
        const int start = blockIdx.x * PCHUNK;

        hist[t] = 0; hist[t + 256] = 0;
        __syncthreads();
#pragma unroll
        for (int j = 0; j < PCHUNK / 256; ++j) {
            int e = start + j * 256 + t;
            if (e < nE) atomicAdd(&hist[dst[e] >> 8], 1);
        }
        __syncthreads();
        const int c0 = hist[t];
        const int c1 = hist[t + 256];
        s[t] = c0; s[t + 256] = c1;
        __syncthreads();
        // 512-wide inclusive scan with 256 threads
#pragma unroll
        for (int off = 1; off <= 256; off <<= 1) {
            int x0 = (t >= off) ? s[t - off] : 0;
            int x1 = s[t + 256 - off];
            __syncthreads();
            s[t] += x0; s[t + 256] += x1;
            __syncthreads();
        }
        lstart[t]       = s[t] - c0;
        lstart[t + 256] = s[t + 256] - c1;
        curB[t]         = s[t] - c0;
        curB[t + 256]   = s[t + 256] - c1;
        gbase[t]        = c0 ? atomicAdd(&bcursor[t],       c0) : 0;
        gbase[t + 256]  = c1 ? atomicAdd(&bcursor[t + 256], c1) : 0;
        __syncthreads();

#pragma unroll
        for (int j = 0; j < PCHUNK / 256; ++j) {
            int e = start + j * 256 + t;
            if (e < nE) {
                int d  = dst[e];
                int sv = src[e];
                int b  = d >> 8;
                int pos = atomicAdd(&curB[b], 1);
                reorder[pos] = ((unsigned)sv << 8) | ((unsigned)d & 255u);
            }
        }
        __syncthreads();

        // flush: one thread per bucket writes its contiguous run
        for (int b = t; b < NBUCK; b += 256) {
            int st = lstart[b];
            int en = curB[b];
            int gb = gbase[b];
            for (int k = st; k < en; ++k)
                pe[gb + (k - st)] = reorder[k];
        }
    } else {
        // ---------------- layer-0 GEMM ----------------
        const int bid  = blockIdx.x - PGRID;
        const int wv   = t >> 6;
        const int lane = t & 63;
        const int q    = lane >> 4;
        const int m    = lane & 15;
        const int rb   = bid * 64 + wv * 16;
        const int arow = rb + m;
        const bool rok = arow < nrows;
        const float* Ar = A + (size_t)arow * IN_F;

        f32x4 acc[8];
#pragma unroll
        for (int nt = 0; nt < 8; ++nt) acc[nt] = (f32x4){0.f, 0.f, 0.f, 0.f};

#pragma unroll
        for (int kt = 0; kt < 4; ++kt) {
            bf16x8 afr = (bf16x8){0, 0, 0, 0, 0, 0, 0, 0};
            if (rok) {
                float4 v0 = *(const float4*)(Ar + kt * 32 + q * 8);
                float4 v1 = *(const float4*)(Ar + kt * 32 + q * 8 + 4);
                afr[0] = (short)f2bf(v0.x); afr[1] = (short)f2bf(v0.y);
                afr[2] = (short)f2bf(v0.z); afr[3] = (short)f2bf(v0.w);
                afr[4] = (short)f2bf(v1.x); afr[5] = (short)f2bf(v1.y);
                afr[6] = (short)f2bf(v1.z); afr[7] = (short)f2bf(v1.w);
            }
#pragma unroll
            for (int nt = 0; nt < 8; ++nt) {
                bf16x8 bfr = *(const bf16x8*)(Wp + ((size_t)(nt * 4 + kt) * 64 + lane) * 8);
                acc[nt] = __builtin_amdgcn_mfma_f32_16x16x32_bf16(afr, bfr, acc[nt], 0, 0, 0);
            }
        }

        float pel[16], per[16];
#pragma unroll
        for (int i = 0; i < 16; ++i) { pel[i] = 0.f; per[i] = 0.f; }

#pragma unroll
        for (int nt = 0; nt < 8; ++nt) {
            const int col = nt * 16 + m;
            const float alv = al[col];
            const float arv = ar[col];
            const int h = nt >> 1;
#pragma unroll
            for (int reg = 0; reg < 4; ++reg) {
                int row = rb + q * 4 + reg;
                float a = acc[nt][reg];
                if (row < nrows) featb[(size_t)row * 128 + col] = f2bf(a);
                pel[reg * 4 + h] += a * alv;
                per[reg * 4 + h] += a * arv;
            }
        }
#pragma unroll
        for (int sh = 8; sh > 0; sh >>= 1) {
#pragma unroll
            for (int i = 0; i < 16; ++i) {
                pel[i] += __shfl_down(pel[i], sh);
                per[i] += __shfl_down(per[i], sh);
            }
        }
        if (m == 0) {
#pragma unroll
            for (int reg = 0; reg < 4; ++reg) {
                int row = rb + q * 4 + reg;
                if (row < nrows) {
#pragma unroll
                    for (int h = 0; h < 4; ++h) {
                        el[row * 4 + h] = pel[reg * 4 + h];
                        er[row * 4 + h] = per[reg * 4 + h];
                    }
                }
            }
        }
    }
}

// ---------------------------------------------------------------------------
// K3: per-bucket finalize — degree histogram + local scan -> rowptr/deg,
// within-bucket sort -> sorted_boff (BYTE offsets src*256, = ed & ~255).
// ---------------------------------------------------------------------------
__global__ __launch_bounds__(256) void bucket_finalize(const unsigned int* __restrict__ pe,
                                                       const int* __restrict__ bcursor,
                                                       int* __restrict__ rowptr,
                                                       int* __restrict__ deg,
                                                       int* __restrict__ sorted_boff) {
    __shared__ int deg_l[256];
    __shared__ int s[256];
    __shared__ int cur[256];

    const int b  = blockIdx.x;
    const int t  = threadIdx.x;
    const int base = b * BCAP;
    const int cnt  = bcursor[b] - base;
    const int n    = b * 256 + t;

    deg_l[t] = 0;
    __syncthreads();
    for (int i = t; i < cnt; i += 256)
        atomicAdd(&deg_l[pe[base + i] & 255u], 1);
    __syncthreads();

    const int dv = deg_l[t];
    s[t] = dv;
    __syncthreads();
#pragma unroll
    for (int off = 1; off < 256; off <<= 1) {
        int x = (t >= off) ? s[t - off] : 0;
        __syncthreads();
        s[t] += x;
        __syncthreads();
    }
    const int off_l = s[t] - dv;
    if (n < N_NODES) {
        rowptr[n] = base + off_l;
        deg[n]    = dv;
    }
    cur[t] = off_l;
    __syncthreads();

    for (int i = t; i < cnt; i += 256) {
        unsigned int ed = pe[base + i];
        int pos = atomicAdd(&cur[ed & 255u], 1);
        sorted_boff[base + pos] = (int)(ed & 0xFFFFFF00u);   // src*256 byte offset
    }
}

// ---------------------------------------------------------------------------
// MFMA GEMM, bf16 A (layer 1): featb = Ab @ Wp, el/er fused. W1p staged in LDS.
// ---------------------------------------------------------------------------
__global__ __launch_bounds__(256) void gemm128_mfma_bf16(const unsigned short* __restrict__ Ab,
                                                         const unsigned short* __restrict__ Wp,
                                                         const float* __restrict__ al,
                                                         const float* __restrict__ ar,
                                                         unsigned short* __restrict__ featb,
                                                         float* __restrict__ el,
                                                         float* __restrict__ er,
                                                         int nrows) {
    __shared__ int4 wl4[2048];   // 32KB packed W1
    const int t    = threadIdx.x;
#pragma unroll
    for (int w = 0; w < 8; ++w) wl4[w * 256 + t] = ((const int4*)Wp)[w * 256 + t];
    __syncthreads();
    const unsigned short* wl = (const unsigned short*)wl4;

    const int wv   = t >> 6;
    const int lane = t & 63;
    const int q    = lane >> 4;
    const int m    = lane & 15;
    const int rb   = blockIdx.x * 64 + wv * 16;
    const int arow = rb + m;
    const bool rok = arow < nrows;
    const unsigned short* Ar = Ab + (size_t)arow * IN_F;

    f32x4 acc[8];
#pragma unroll
    for (int nt = 0; nt < 8; ++nt) acc[nt] = (f32x4){0.f, 0.f, 0.f, 0.f};

#pragma unroll
    for (int kt = 0; kt < 4; ++kt) {
        bf16x8 afr = (bf16x8){0, 0, 0, 0, 0, 0, 0, 0};
        if (rok) afr = *(const bf16x8*)(Ar + kt * 32 + q * 8);
#pragma unroll
        for (int nt = 0; nt < 8; ++nt) {
            bf16x8 bfr = *(const bf16x8*)(wl + ((size_t)(nt * 4 + kt) * 64 + lane) * 8);
            acc[nt] = __builtin_amdgcn_mfma_f32_16x16x32_bf16(afr, bfr, acc[nt], 0, 0, 0);
        }
    }

    float pel[16], per[16];
#pragma unroll
    for (int i = 0; i < 16; ++i) { pel[i] = 0.f; per[i] = 0.f; }

#pragma unroll
    for (int nt = 0; nt < 8; ++nt) {
        const int col = nt * 16 + m;
        const float alv = al[col];
        const float arv = ar[col];
        const int h = nt >> 1;
#pragma unroll
        for (int reg = 0; reg < 4; ++reg) {
            int row = rb + q * 4 + reg;
            float a = acc[nt][reg];
            if (row < nrows) featb[(size_t)row * 128 + col] = f2bf(a);
            pel[reg * 4 + h] += a * alv;
            per[reg * 4 + h] += a * arv;
        }
    }
#pragma unroll
    for (int sh = 8; sh > 0; sh >>= 1) {
#pragma unroll
        for (int i = 0; i < 16; ++i) {
            pel[i] += __shfl_down(pel[i], sh);
            per[i] += __shfl_down(per[i], sh);
        }
    }
    if (m == 0) {
#pragma unroll
        for (int reg = 0; reg < 4; ++reg) {
            int row = rb + q * 4 + reg;
            if (row < nrows) {
#pragma unroll
                for (int h = 0; h < 4; ++h) {
                    el[row * 4 + h] = pel[reg * 4 + h];
                    er[row * 4 + h] = per[reg * 4 + h];
                }
            }
        }
    }
}

// ---------------------------------------------------------------------------
// MFMA dual GEMM layer 2 (bf16 A): [feat2b(bf16) | res2(f32)] = A @ [W2|resW2].
// ---------------------------------------------------------------------------
__global__ __launch_bounds__(256) void gemm16_mfma(const unsigned short* __restrict__ Ab,
                                                   const unsigned short* __restrict__ Wp,
                                                   const float* __restrict__ al,
                                                   const float* __restrict__ ar,
                                                   unsigned short* __restrict__ feat2b,
                                                   float* __restrict__ res2,
                                                   float* __restrict__ el,
                                                   float* __restrict__ er,
                                                   int nrows) {
    const int t    = threadIdx.x;
    const int wv   = t >> 6;
    const int lane = t & 63;
    const int q    = lane >> 4;
    const int m    = lane & 15;
    const int rb   = blockIdx.x * 64 + wv * 16;
    const int arow = rb + m;
    const bool rok = arow < nrows;
    const unsigned short* Ar = Ab + (size_t)arow * IN_F;

    f32x4 acc0 = (f32x4){0.f, 0.f, 0.f, 0.f};
    f32x4 acc1 = (f32x4){0.f, 0.f, 0.f, 0.f};

#pragma unroll
    for (int kt = 0; kt < 4; ++kt) {
        bf16x8 afr = (bf16x8){0, 0, 0, 0, 0, 0, 0, 0};
        if (rok) afr = *(const bf16x8*)(Ar + kt * 32 + q * 8);
        bf16x8 b0 = *(const bf16x8*)(Wp + ((size_t)(0 * 4 + kt) * 64 + lane) * 8);
        bf16x8 b1 = *(const bf16x8*)(Wp + ((size_t)(1 * 4 + kt) * 64 + lane) * 8);
        acc0 = __builtin_amdgcn_mfma_f32_16x16x32_bf16(afr, b0, acc0, 0, 0, 0);
        acc1 = __builtin_amdgcn_mfma_f32_16x16x32_bf16(afr, b1, acc1, 0, 0, 0);
    }

    float pel[4], per[4];
    const float alv = al[m];
    const float arv = ar[m];
#pragma unroll
    for (int reg = 0; reg < 4; ++reg) {
        int row = rb + q * 4 + reg;
        float a = acc0[reg];
        if (row < nrows) {
            feat2b[(size_t)row * 16 + m] = f2bf(a);
            res2[(size_t)row * 16 + m]   = acc1[reg];
        }
        pel[reg] = a * alv;
        per[reg] = a * arv;
    }
#pragma unroll
    for (int sh = 8; sh > 0; sh >>= 1) {
#pragma unroll
        for (int reg = 0; reg < 4; ++reg) {
            pel[reg] += __shfl_down(pel[reg], sh);
            per[reg] += __shfl_down(per[reg], sh);
        }
    }
    if (m == 0) {
#pragma unroll
        for (int reg = 0; reg < 4; ++reg) {
            int row = rb + q * 4 + reg;
            if (row < nrows) { el[row] = pel[reg]; er[row] = per[reg]; }
        }
    }
}

// ---------------------------------------------------------------------------
// Pull aggregation, H=4, D=32, bf16 gathers, wave per node, bf16 in/out.
//
// v5: persistent grid-stride (AGGBLKS=2048 = 8 blocks/CU, all co-resident).
// 25000 short blocks exceeded the command processor's workgroup dispatch
// rate (occupancy pinned at 75% with no resource limit); persistent blocks
// loop over ~12 node-groups each. Inner per-node code identical to v3.
// ---------------------------------------------------------------------------
__global__ __launch_bounds__(256) void gat_agg128(const int* __restrict__ rowptr,
                                                  const int* __restrict__ deg,
                                                  const int* __restrict__ sorted_boff,
                                                  const float* __restrict__ el,
                                                  const float* __restrict__ er,
                                                  const unsigned short* __restrict__ featb,
                                                  const unsigned short* __restrict__ resb,
                                                  unsigned short* __restrict__ outb) {
    __shared__ __align__(16) int   sS[4][64];
    __shared__ __align__(16) float sW[4][4][68];

    const int wv   = threadIdx.x >> 6;
    const int lane = threadIdx.x & 63;
    const int h    = lane >> 4;
    const unsigned int lane4 = (unsigned int)(lane << 2);
    const char* fb = (const char*)featb;
    const char* eb = (const char*)el;

    for (int blk = blockIdx.x; blk < N_NODES / 4; blk += AGGBLKS) {
        const int nd = blk * 4 + wv;
        const int dg = deg[nd];
        const int r0 = rowptr[nd];
        const float4 er4 = *(const float4*)(er + nd * 4);

        float dx = 0.f, dy = 0.f, dz = 0.f, dw = 0.f;
        float ax = 0.f, ay = 0.f;

        for (int base = 0; base < dg; base += 64) {
            int m = dg - base; if (m > 64) m = 64;

            // ---- stage: each lane owns one edge ----
            int boff = 0;
            float4 w4 = {0.f, 0.f, 0.f, 0.f};
            if (lane < m) {
                boff = sorted_boff[r0 + base + lane];
                float4 e4 = *(const float4*)(eb + (unsigned int)(boff >> 4));
                float t_;
                t_ = e4.x + er4.x; t_ = t_ > 0.f ? t_ : NEG_SLOPE * t_; w4.x = __expf(t_);
                t_ = e4.y + er4.y; t_ = t_ > 0.f ? t_ : NEG_SLOPE * t_; w4.y = __expf(t_);
                t_ = e4.z + er4.z; t_ = t_ > 0.f ? t_ : NEG_SLOPE * t_; w4.z = __expf(t_);
                t_ = e4.w + er4.w; t_ = t_ > 0.f ? t_ : NEG_SLOPE * t_; w4.w = __expf(t_);
            }
            // wave-synchronous: same wave writes and reads its slice
            sS[wv][lane]    = boff;
            sW[wv][0][lane] = w4.x;
            sW[wv][1][lane] = w4.y;
            sW[wv][2][lane] = w4.z;
            sW[wv][3][lane] = w4.w;
            dx += w4.x; dy += w4.y; dz += w4.z; dw += w4.w;

            // ---- consume: 8 edges per group, no conditionals ----
            const int mr = (m + 7) & ~7;
            for (int i = 0; i < mr; i += 8) {
                const int4   sa = *(const int4*)(&sS[wv][i]);
                const int4   sb = *(const int4*)(&sS[wv][i + 4]);
                const float4 wa = *(const float4*)(&sW[wv][h][i]);
                const float4 wb = *(const float4*)(&sW[wv][h][i + 4]);

                unsigned int u0 = ld_u32(fb, (unsigned int)sa.x + lane4);
                unsigned int u1 = ld_u32(fb, (unsigned int)sa.y + lane4);
                unsigned int u2 = ld_u32(fb, (unsigned int)sa.z + lane4);
                unsigned int u3 = ld_u32(fb, (unsigned int)sa.w + lane4);
                unsigned int u4 = ld_u32(fb, (unsigned int)sb.x + lane4);
                unsigned int u5 = ld_u32(fb, (unsigned int)sb.y + lane4);
                unsigned int u6 = ld_u32(fb, (unsigned int)sb.z + lane4);
                unsigned int u7 = ld_u32(fb, (unsigned int)sb.w + lane4);

                ax += wa.x * __uint_as_float(u0 << 16);
                ay += wa.x * __uint_as_float(u0 & 0xFFFF0000u);
                ax += wa.y * __uint_as_float(u1 << 16);
                ay += wa.y * __uint_as_float(u1 & 0xFFFF0000u);
                ax += wa.z * __uint_as_float(u2 << 16);
                ay += wa.z * __uint_as_float(u2 & 0xFFFF0000u);
                ax += wa.w * __uint_as_float(u3 << 16);
                ay += wa.w * __uint_as_float(u3 & 0xFFFF0000u);
                ax += wb.x * __uint_as_float(u4 << 16);
                ay += wb.x * __uint_as_float(u4 & 0xFFFF0000u);
                ax += wb.y * __uint_as_float(u5 << 16);
                ay += wb.y * __uint_as_float(u5 & 0xFFFF0000u);
                ax += wb.z * __uint_as_float(u6 << 16);
                ay += wb.z * __uint_as_float(u6 & 0xFFFF0000u);
                ax += wb.w * __uint_as_float(u7 << 16);
                ay += wb.w * __uint_as_float(u7 & 0xFFFF0000u);
            }
        }

        // den: butterfly-reduce the staged weight sums across all 64 lanes
#pragma unroll
        for (int sh = 1; sh < 64; sh <<= 1) {
            dx += __shfl_xor(dx, sh);
            dy += __shfl_xor(dy, sh);
            dz += __shfl_xor(dz, sh);
            dw += __shfl_xor(dw, sh);
        }
        float den = (h == 0) ? dx : (h == 1) ? dy : (h == 2) ? dz : dw;

        float scale = den > 0.f ? 1.f / den : 0.f;
        float ox = ax * scale, oy = ay * scale;
        size_t o0 = (size_t)nd * 128 + lane * 2;
        if (resb) {
            ushort2 rv = *(const ushort2*)(resb + o0);
            ox += bf2f(rv.x);
            oy += bf2f(rv.y);
        }
        ox = fmaxf(ox, 0.f);
        oy = fmaxf(oy, 0.f);
        ushort2 ou;
        ou.x = f2bf(ox);
        ou.y = f2bf(oy);
        *(ushort2*)(outb + o0) = ou;
    }
}

// ---------------------------------------------------------------------------
// Pull aggregation, H=1, C=16: persistent grid-stride; wave per node, LDS
// staging, 8 edge-groups of 8 lanes; lane owns a feature pair. f32 out (+res2).
// sorted_boff holds src*256; feat2b byte = boff>>3, el byte = boff>>6.
// ---------------------------------------------------------------------------
__global__ __launch_bounds__(256) void gat_agg16(const int* __restrict__ rowptr,
                                                 const int* __restrict__ deg,
                                                 const int* __restrict__ sorted_boff,
                                                 const float* __restrict__ el,
                                                 const float* __restrict__ er,
                                                 const unsigned short* __restrict__ feat2b,
                                                 const float* __restrict__ res,
                                                 float* __restrict__ out) {
    __shared__ int   sS[4][64];
    __shared__ float sW[4][64];

    const int wv   = threadIdx.x >> 6;
    const int lane = threadIdx.x & 63;
    const int g    = lane >> 3;
    const unsigned int flane4 = (unsigned int)((lane & 7) << 2);
    const char* f2base = (const char*)feat2b;
    const char* eb = (const char*)el;

    for (int blk = blockIdx.x; blk < N_NODES / 4; blk += AGGBLKS) {
        const int nd = blk * 4 + wv;
        const int dg = deg[nd];
        const int r0 = rowptr[nd];
        const float erd = er[nd];

        float ax = 0.f, ay = 0.f, den = 0.f;

        for (int base = 0; base < dg; base += 64) {
            int m = dg - base; if (m > 64) m = 64;
            if (lane < m) {
                int boff = sorted_boff[r0 + base + lane];
                sS[wv][lane] = boff;
                float v = *(const float*)(eb + (unsigned int)(boff >> 6)) + erd;
                v = v > 0.f ? v : NEG_SLOPE * v;
                sW[wv][lane] = __expf(v);
            }
            for (int i = g; i < m; i += 8) {
                int bo  = sS[wv][i];
                float w = sW[wv][i];
                den += w;
                unsigned int u = *(const unsigned int*)(f2base + (unsigned int)(bo >> 3) + flane4);
                ax += w * __uint_as_float(u << 16);
                ay += w * __uint_as_float(u & 0xFFFF0000u);
            }
        }

        ax += __shfl_down(ax, 32); ay += __shfl_down(ay, 32); den += __shfl_down(den, 32);
        ax += __shfl_down(ax, 16); ay += __shfl_down(ay, 16); den += __shfl_down(den, 16);
        ax += __shfl_down(ax, 8);  ay += __shfl_down(ay, 8);  den += __shfl_down(den, 8);

        if (lane < 8) {
            float scale = den > 0.f ? 1.f / den : 0.f;
            size_t o0 = (size_t)nd * 16 + ((lane & 7) << 1);
            float2 o;
            o.x = ax * scale + res[o0];
            o.y = ay * scale + res[o0 + 1];
            *(float2*)(out + o0) = o;
        }
    }
}

// ---------------------------------------------------------------------------
extern "C" void kernel_launch(void* const* d_in, const int* in_sizes, int n_in,
                              void* d_out, int out_size, void* d_ws, size_t ws_size,
                              hipStream_t stream) {
    const float* inputs = (const float*)d_in[0];
    const int*   src    = (const int*)d_in[1];
    const int*   dst    = (const int*)d_in[2];
    const float* W0     = (const float*)d_in[3];
    const float* al0    = (const float*)d_in[4];
    const float* ar0    = (const float*)d_in[5];
    const float* W1     = (const float*)d_in[6];
    const float* al1    = (const float*)d_in[7];
    const float* ar1    = (const float*)d_in[8];
    const float* W2     = (const float*)d_in[9];
    const float* al2    = (const float*)d_in[10];
    const float* ar2    = (const float*)d_in[11];
    const float* resW2  = (const float*)d_in[12];
    float* out = (float*)d_out;

    const size_t NF = (size_t)N_NODES * 128;
    float* ws   = (float*)d_ws;
    float* el   = ws;                                  // N*4
    float* er   = el + (size_t)N_NODES * 4;            // N*4
    float* res2 = er + (size_t)N_NODES * 4;            // N*16
    unsigned short* hbufb  = (unsigned short*)(res2 + (size_t)N_NODES * 16);  // N*128 bf16
    unsigned short* featb  = hbufb + NF;               // N*128 bf16
    unsigned short* feat2b = featb + NF;               // N*16 bf16
    unsigned short* W0p    = feat2b + (size_t)N_NODES * 16;  // 16384
    unsigned short* W1p    = W0p + 16384;                    // 16384
    unsigned short* W2p    = W1p + 16384;                    // 8192
    int* iws = (int*)(W2p + 8192);
    unsigned int* pe = (unsigned int*)iws;             // NBUCK*BCAP padded
    int* sorted_boff = iws + NBUCK * BCAP;             // NBUCK*BCAP padded
    int* deg         = sorted_boff + NBUCK * BCAP;     // N
    int* rowptr      = deg + N_NODES;                  // N
    int* bcursor     = rowptr + N_NODES;               // 512

    dim3 blk(256);

    // ---- K1: cursor init + weight pack ----
    init_pack<<<162, blk, 0, stream>>>(bcursor, W0, W1, W2, resW2, W0p, W1p, W2p);
    // ---- K2: partition + layer-0 GEMM ----
    part_gemm0<<<PGRID + GEMMGRID, blk, 0, stream>>>(src, dst, bcursor, pe, N_EDGES,
                                                     inputs, W0p, al0, ar0, featb,
                                                     el, er, N_NODES);
    // ---- K3: finalize CSR ----
    bucket_finalize<<<PGRID, blk, 0, stream>>>(pe, bcursor, rowptr, deg, sorted_boff);

    // ---- layer 0 aggregation ----
    gat_agg128<<<AGGBLKS, blk, 0, stream>>>(rowptr, deg, sorted_boff, el, er, featb,
                                            nullptr, hbufb);

    // ---- layer 1 ----
    gemm128_mfma_bf16<<<GEMMGRID, blk, 0, stream>>>(hbufb, W1p, al1, ar1, featb,
                                                    el, er, N_NODES);
    gat_agg128<<<AGGBLKS, blk, 0, stream>>>(rowptr, deg, sorted_boff, el, er, featb,
                                            hbufb, hbufb);

    // ---- layer 2 ----
    gemm16_mfma<<<GEMMGRID, blk, 0, stream>>>(hbufb, W2p, al2, ar2, feat2b, res2,
                                              el, er, N_NODES);
    gat_agg16<<<AGGBLKS, blk, 0, stream>>>(rowptr, deg, sorted_boff, el, er, feat2b,
                                           res2, out);
}

// Round 5
// 385.314 us; speedup vs baseline: 1.0875x; 1.0875x over previous
//
#include <hip/hip_runtime.h>

#define N_NODES 100000
#define N_EDGES 1600000
#define IN_F    128
#define NEG_SLOPE 0.2f
#define NBUCK   512                 // bucket = dst>>8; 391 active
#define BCAP    5120                // padded bucket capacity (mean 4096, +16 sigma)
#define PCHUNK  4096                // edges per partition block
#define PGRID   391                 // ceil(N_EDGES / PCHUNK)
#define GEMMGRID 1563               // ceil(N_NODES / 64)

typedef __attribute__((ext_vector_type(8))) short bf16x8;
typedef __attribute__((ext_vector_type(4))) float f32x4;

__device__ __forceinline__ float bf2f(unsigned short u) {
    return __uint_as_float(((unsigned int)u) << 16);
}

// f32 -> bf16 round-to-nearest-even
__device__ __forceinline__ unsigned short f2bf(float f) {
    unsigned int u = __float_as_uint(f);
    u += 0x7FFFu + ((u >> 16) & 1u);
    return (unsigned short)(u >> 16);
}

// uniform-base + 32-bit-offset loads: encourage global_load saddr form
__device__ __forceinline__ unsigned int ld_u32(const char* base, unsigned int off) {
    return *(const unsigned int*)(base + off);
}
__device__ __forceinline__ uint2 ld_u64(const char* base, unsigned int off) {
    return *(const uint2*)(base + off);
}

// ---------------------------------------------------------------------------
// K1: cursor init (blocks 0..1) + weight pack (blocks 2..161).
// Pack layout: Wp[((nt*4+kt)*64+lane)*8+j] = W[kt*32+(lane>>4)*8+j][nt*16+(lane&15)]
// ---------------------------------------------------------------------------
__global__ __launch_bounds__(256) void init_pack(int* __restrict__ bcursor,
                                                 const float* __restrict__ W0,
                                                 const float* __restrict__ W1,
                                                 const float* __restrict__ W2,
                                                 const float* __restrict__ rW2,
                                                 unsigned short* __restrict__ W0p,
                                                 unsigned short* __restrict__ W1p,
                                                 unsigned short* __restrict__ W2p) {
    const int t = threadIdx.x;
    if (blockIdx.x < 2) {
        int i = blockIdx.x * 256 + t;
        if (i < NBUCK) bcursor[i] = i * BCAP;
        return;
    }
    int gid = (blockIdx.x - 2) * 256 + t;            // < 40960
    const float* W;
    unsigned short* Wp;
    int idx, ncols;
    if (gid < 16384)      { W = W0; Wp = W0p; idx = gid;          ncols = 128; }
    else if (gid < 32768) { W = W1; Wp = W1p; idx = gid - 16384;  ncols = 128; }
    else                  { W = W2; Wp = W2p; idx = gid - 32768;  ncols = 32;  }
    int j  = idx & 7;
    int l  = (idx >> 3) & 63;
    int kt = (idx >> 9) & 3;
    int nt = idx >> 11;
    int k  = kt * 32 + (l >> 4) * 8 + j;
    int n  = nt * 16 + (l & 15);
    float v;
    if (ncols == 128) v = W[k * 128 + n];
    else              v = (n < 16) ? W[k * 16 + n] : rW2[k * 16 + (n - 16)];
    Wp[idx] = f2bf(v);
}

// ---------------------------------------------------------------------------
// K2: edge partition into padded buckets (blocks [0,PGRID)) + layer-0 MFMA
// GEMM (blocks [PGRID, PGRID+GEMMGRID)).
// ---------------------------------------------------------------------------
__global__ __launch_bounds__(256) void part_gemm0(const int* __restrict__ src,
                                                  const int* __restrict__ dst,
                                                  int* __restrict__ bcursor,
                                                  unsigned int* __restrict__ pe, int nE,
                                                  const float* __restrict__ A,
                                                  const unsigned short* __restrict__ Wp,
                                                  const float* __restrict__ al,
                                                  const float* __restrict__ ar,
                                                  unsigned short* __restrict__ featb,
                                                  float* __restrict__ el,
                                                  float* __restrict__ er,
                                                  int nrows) {
    __shared__ int hist[NBUCK];
    __shared__ int lstart[NBUCK];
    __shared__ int gbase[NBUCK];
    __shared__ int curB[NBUCK];
    __shared__ int s[NBUCK];
    __shared__ unsigned int reorder[PCHUNK];

    const int t = threadIdx.x;

    if (blockIdx.x < PGRID) {
        const int start = blockIdx.x * PCHUNK;

        hist[t] = 0; hist[t + 256] = 0;
        __syncthreads();
#pragma unroll
        for (int j = 0; j < PCHUNK / 256; ++j) {
            int e = start + j * 256 + t;
            if (e < nE) atomicAdd(&hist[dst[e] >> 8], 1);
        }
        __syncthreads();
        const int c0 = hist[t];
        const int c1 = hist[t + 256];
        s[t] = c0; s[t + 256] = c1;
        __syncthreads();
        // 512-wide inclusive scan with 256 threads
#pragma unroll
        for (int off = 1; off <= 256; off <<= 1) {
            int x0 = (t >= off) ? s[t - off] : 0;
            int x1 = s[t + 256 - off];
            __syncthreads();
            s[t] += x0; s[t + 256] += x1;
            __syncthreads();
        }
        lstart[t]       = s[t] - c0;
        lstart[t + 256] = s[t + 256] - c1;
        curB[t]         = s[t] - c0;
        curB[t + 256]   = s[t + 256] - c1;
        gbase[t]        = c0 ? atomicAdd(&bcursor[t],       c0) : 0;
        gbase[t + 256]  = c1 ? atomicAdd(&bcursor[t + 256], c1) : 0;
        __syncthreads();

#pragma unroll
        for (int j = 0; j < PCHUNK / 256; ++j) {
            int e = start + j * 256 + t;
            if (e < nE) {
                int d  = dst[e];
                int sv = src[e];
                int b  = d >> 8;
                int pos = atomicAdd(&curB[b], 1);
                reorder[pos] = ((unsigned)sv << 8) | ((unsigned)d & 255u);
            }
        }
        __syncthreads();

        // flush: one thread per bucket writes its contiguous run
        for (int b = t; b < NBUCK; b += 256) {
            int st = lstart[b];
            int en = curB[b];
            int gb = gbase[b];
            for (int k = st; k < en; ++k)
                pe[gb + (k - st)] = reorder[k];
        }
    } else {
        // ---------------- layer-0 GEMM ----------------
        const int bid  = blockIdx.x - PGRID;
        const int wv   = t >> 6;
        const int lane = t & 63;
        const int q    = lane >> 4;
        const int m    = lane & 15;
        const int rb   = bid * 64 + wv * 16;
        const int arow = rb + m;
        const bool rok = arow < nrows;
        const float* Ar = A + (size_t)arow * IN_F;

        f32x4 acc[8];
#pragma unroll
        for (int nt = 0; nt < 8; ++nt) acc[nt] = (f32x4){0.f, 0.f, 0.f, 0.f};

#pragma unroll
        for (int kt = 0; kt < 4; ++kt) {
            bf16x8 afr = (bf16x8){0, 0, 0, 0, 0, 0, 0, 0};
            if (rok) {
                float4 v0 = *(const float4*)(Ar + kt * 32 + q * 8);
                float4 v1 = *(const float4*)(Ar + kt * 32 + q * 8 + 4);
                afr[0] = (short)f2bf(v0.x); afr[1] = (short)f2bf(v0.y);
                afr[2] = (short)f2bf(v0.z); afr[3] = (short)f2bf(v0.w);
                afr[4] = (short)f2bf(v1.x); afr[5] = (short)f2bf(v1.y);
                afr[6] = (short)f2bf(v1.z); afr[7] = (short)f2bf(v1.w);
            }
#pragma unroll
            for (int nt = 0; nt < 8; ++nt) {
                bf16x8 bfr = *(const bf16x8*)(Wp + ((size_t)(nt * 4 + kt) * 64 + lane) * 8);
                acc[nt] = __builtin_amdgcn_mfma_f32_16x16x32_bf16(afr, bfr, acc[nt], 0, 0, 0);
            }
        }

        float pel[16], per[16];
#pragma unroll
        for (int i = 0; i < 16; ++i) { pel[i] = 0.f; per[i] = 0.f; }

#pragma unroll
        for (int nt = 0; nt < 8; ++nt) {
            const int col = nt * 16 + m;
            const float alv = al[col];
            const float arv = ar[col];
            const int h = nt >> 1;
#pragma unroll
            for (int reg = 0; reg < 4; ++reg) {
                int row = rb + q * 4 + reg;
                float a = acc[nt][reg];
                if (row < nrows) featb[(size_t)row * 128 + col] = f2bf(a);
                pel[reg * 4 + h] += a * alv;
                per[reg * 4 + h] += a * arv;
            }
        }
#pragma unroll
        for (int sh = 8; sh > 0; sh >>= 1) {
#pragma unroll
            for (int i = 0; i < 16; ++i) {
                pel[i] += __shfl_down(pel[i], sh);
                per[i] += __shfl_down(per[i], sh);
            }
        }
        if (m == 0) {
#pragma unroll
            for (int reg = 0; reg < 4; ++reg) {
                int row = rb + q * 4 + reg;
                if (row < nrows) {
#pragma unroll
                    for (int h = 0; h < 4; ++h) {
                        el[row * 4 + h] = pel[reg * 4 + h];
                        er[row * 4 + h] = per[reg * 4 + h];
                    }
                }
            }
        }
    }
}

// ---------------------------------------------------------------------------
// K3: per-bucket finalize — degree histogram + local scan -> rowptr/deg,
// within-bucket sort -> sorted_boff (BYTE offsets src*256, = ed & ~255).
// ---------------------------------------------------------------------------
__global__ __launch_bounds__(256) void bucket_finalize(const unsigned int* __restrict__ pe,
                                                       const int* __restrict__ bcursor,
                                                       int* __restrict__ rowptr,
                                                       int* __restrict__ deg,
                                                       int* __restrict__ sorted_boff) {
    __shared__ int deg_l[256];
    __shared__ int s[256];
    __shared__ int cur[256];

    const int b  = blockIdx.x;
    const int t  = threadIdx.x;
    const int base = b * BCAP;
    const int cnt  = bcursor[b] - base;
    const int n    = b * 256 + t;

    deg_l[t] = 0;
    __syncthreads();
    for (int i = t; i < cnt; i += 256)
        atomicAdd(&deg_l[pe[base + i] & 255u], 1);
    __syncthreads();

    const int dv = deg_l[t];
    s[t] = dv;
    __syncthreads();
#pragma unroll
    for (int off = 1; off < 256; off <<= 1) {
        int x = (t >= off) ? s[t - off] : 0;
        __syncthreads();
        s[t] += x;
        __syncthreads();
    }
    const int off_l = s[t] - dv;
    if (n < N_NODES) {
        rowptr[n] = base + off_l;
        deg[n]    = dv;
    }
    cur[t] = off_l;
    __syncthreads();

    for (int i = t; i < cnt; i += 256) {
        unsigned int ed = pe[base + i];
        int pos = atomicAdd(&cur[ed & 255u], 1);
        sorted_boff[base + pos] = (int)(ed & 0xFFFFFF00u);   // src*256 byte offset
    }
}

// ---------------------------------------------------------------------------
// MFMA GEMM, bf16 A (layer 1): featb = Ab @ Wp, el/er fused. W1p staged in LDS.
// ---------------------------------------------------------------------------
__global__ __launch_bounds__(256) void gemm128_mfma_bf16(const unsigned short* __restrict__ Ab,
                                                         const unsigned short* __restrict__ Wp,
                                                         const float* __restrict__ al,
                                                         const float* __restrict__ ar,
                                                         unsigned short* __restrict__ featb,
                                                         float* __restrict__ el,
                                                         float* __restrict__ er,
                                                         int nrows) {
    __shared__ int4 wl4[2048];   // 32KB packed W1
    const int t    = threadIdx.x;
#pragma unroll
    for (int w = 0; w < 8; ++w) wl4[w * 256 + t] = ((const int4*)Wp)[w * 256 + t];
    __syncthreads();
    const unsigned short* wl = (const unsigned short*)wl4;

    const int wv   = t >> 6;
    const int lane = t & 63;
    const int q    = lane >> 4;
    const int m    = lane & 15;
    const int rb   = blockIdx.x * 64 + wv * 16;
    const int arow = rb + m;
    const bool rok = arow < nrows;
    const unsigned short* Ar = Ab + (size_t)arow * IN_F;

    f32x4 acc[8];
#pragma unroll
    for (int nt = 0; nt < 8; ++nt) acc[nt] = (f32x4){0.f, 0.f, 0.f, 0.f};

#pragma unroll
    for (int kt = 0; kt < 4; ++kt) {
        bf16x8 afr = (bf16x8){0, 0, 0, 0, 0, 0, 0, 0};
        if (rok) afr = *(const bf16x8*)(Ar + kt * 32 + q * 8);
#pragma unroll
        for (int nt = 0; nt < 8; ++nt) {
            bf16x8 bfr = *(const bf16x8*)(wl + ((size_t)(nt * 4 + kt) * 64 + lane) * 8);
            acc[nt] = __builtin_amdgcn_mfma_f32_16x16x32_bf16(afr, bfr, acc[nt], 0, 0, 0);
        }
    }

    float pel[16], per[16];
#pragma unroll
    for (int i = 0; i < 16; ++i) { pel[i] = 0.f; per[i] = 0.f; }

#pragma unroll
    for (int nt = 0; nt < 8; ++nt) {
        const int col = nt * 16 + m;
        const float alv = al[col];
        const float arv = ar[col];
        const int h = nt >> 1;
#pragma unroll
        for (int reg = 0; reg < 4; ++reg) {
            int row = rb + q * 4 + reg;
            float a = acc[nt][reg];
            if (row < nrows) featb[(size_t)row * 128 + col] = f2bf(a);
            pel[reg * 4 + h] += a * alv;
            per[reg * 4 + h] += a * arv;
        }
    }
#pragma unroll
    for (int sh = 8; sh > 0; sh >>= 1) {
#pragma unroll
        for (int i = 0; i < 16; ++i) {
            pel[i] += __shfl_down(pel[i], sh);
            per[i] += __shfl_down(per[i], sh);
        }
    }
    if (m == 0) {
#pragma unroll
        for (int reg = 0; reg < 4; ++reg) {
            int row = rb + q * 4 + reg;
            if (row < nrows) {
#pragma unroll
                for (int h = 0; h < 4; ++h) {
                    el[row * 4 + h] = pel[reg * 4 + h];
                    er[row * 4 + h] = per[reg * 4 + h];
                }
            }
        }
    }
}

// ---------------------------------------------------------------------------
// MFMA dual GEMM layer 2 (bf16 A): [feat2b(bf16) | res2(f32)] = A @ [W2|resW2].
// ---------------------------------------------------------------------------
__global__ __launch_bounds__(256) void gemm16_mfma(const unsigned short* __restrict__ Ab,
                                                   const unsigned short* __restrict__ Wp,
                                                   const float* __restrict__ al,
                                                   const float* __restrict__ ar,
                                                   unsigned short* __restrict__ feat2b,
                                                   float* __restrict__ res2,
                                                   float* __restrict__ el,
                                                   float* __restrict__ er,
                                                   int nrows) {
    const int t    = threadIdx.x;
    const int wv   = t >> 6;
    const int lane = t & 63;
    const int q    = lane >> 4;
    const int m    = lane & 15;
    const int rb   = blockIdx.x * 64 + wv * 16;
    const int arow = rb + m;
    const bool rok = arow < nrows;
    const unsigned short* Ar = Ab + (size_t)arow * IN_F;

    f32x4 acc0 = (f32x4){0.f, 0.f, 0.f, 0.f};
    f32x4 acc1 = (f32x4){0.f, 0.f, 0.f, 0.f};

#pragma unroll
    for (int kt = 0; kt < 4; ++kt) {
        bf16x8 afr = (bf16x8){0, 0, 0, 0, 0, 0, 0, 0};
        if (rok) afr = *(const bf16x8*)(Ar + kt * 32 + q * 8);
        bf16x8 b0 = *(const bf16x8*)(Wp + ((size_t)(0 * 4 + kt) * 64 + lane) * 8);
        bf16x8 b1 = *(const bf16x8*)(Wp + ((size_t)(1 * 4 + kt) * 64 + lane) * 8);
        acc0 = __builtin_amdgcn_mfma_f32_16x16x32_bf16(afr, b0, acc0, 0, 0, 0);
        acc1 = __builtin_amdgcn_mfma_f32_16x16x32_bf16(afr, b1, acc1, 0, 0, 0);
    }

    float pel[4], per[4];
    const float alv = al[m];
    const float arv = ar[m];
#pragma unroll
    for (int reg = 0; reg < 4; ++reg) {
        int row = rb + q * 4 + reg;
        float a = acc0[reg];
        if (row < nrows) {
            feat2b[(size_t)row * 16 + m] = f2bf(a);
            res2[(size_t)row * 16 + m]   = acc1[reg];
        }
        pel[reg] = a * alv;
        per[reg] = a * arv;
    }
#pragma unroll
    for (int sh = 8; sh > 0; sh >>= 1) {
#pragma unroll
        for (int reg = 0; reg < 4; ++reg) {
            pel[reg] += __shfl_down(pel[reg], sh);
            per[reg] += __shfl_down(per[reg], sh);
        }
    }
    if (m == 0) {
#pragma unroll
        for (int reg = 0; reg < 4; ++reg) {
            int row = rb + q * 4 + reg;
            if (row < nrows) { el[row] = pel[reg]; er[row] = per[reg]; }
        }
    }
}

// ---------------------------------------------------------------------------
// Pull aggregation, H=4, D=32, bf16 gathers, wave per node, bf16 in/out.
//
// v6: paired-edge dwordx2 gathers. Lanes 0-31 own edge i, lanes 32-63 own
// edge i+1; each lane loads 8B of its row (rows still read as full
// contiguous 256B — same coalescing as always). Per 8 edges: 4 loads
// (was 8), 4 addr adds (was 8), 2 ds_read_b128 (was 4). Halves the vmem
// instruction count -> doubles bytes in flight per vmcnt slot. Parity-split
// LDS (sSp[parity][pair], sW2[h][parity][pair]) keeps reads broadcast-b128.
// One shfl_xor(32) x4 merges parities at the end.
// ---------------------------------------------------------------------------
__global__ __launch_bounds__(256) void gat_agg128(const int* __restrict__ rowptr,
                                                  const int* __restrict__ deg,
                                                  const int* __restrict__ sorted_boff,
                                                  const float* __restrict__ el,
                                                  const float* __restrict__ er,
                                                  const unsigned short* __restrict__ featb,
                                                  const unsigned short* __restrict__ resb,
                                                  unsigned short* __restrict__ outb) {
    __shared__ __align__(16) int   sSp[4][2][32];     // [wv][parity][pair]
    __shared__ __align__(16) float sW2[4][4][2][36];  // [wv][head][parity][pair+pad]

    const int wv   = threadIdx.x >> 6;
    const int lane = threadIdx.x & 63;
    const int half = lane >> 5;                 // edge parity this lane consumes
    const int sub  = lane & 31;                 // sub-lane: owns features 4*sub..4*sub+3
    const int h    = sub >> 3;                  // head of those features
    const unsigned int lane8 = (unsigned int)(sub << 3);   // byte offset in row
    const int nd   = blockIdx.x * 4 + wv;

    const int dg = deg[nd];
    const int r0 = rowptr[nd];
    const float4 er4 = *(const float4*)(er + nd * 4);
    const char* fb = (const char*)featb;
    const char* eb = (const char*)el;

    float dx = 0.f, dy = 0.f, dz = 0.f, dw = 0.f;
    float a0 = 0.f, a1 = 0.f, a2 = 0.f, a3 = 0.f;

    for (int base = 0; base < dg; base += 64) {
        int m = dg - base; if (m > 64) m = 64;

        // ---- stage: each lane owns one edge ----
        int boff = 0;
        float4 w4 = {0.f, 0.f, 0.f, 0.f};
        if (lane < m) {
            boff = sorted_boff[r0 + base + lane];
            float4 e4 = *(const float4*)(eb + (unsigned int)(boff >> 4));
            float t_;
            t_ = e4.x + er4.x; t_ = t_ > 0.f ? t_ : NEG_SLOPE * t_; w4.x = __expf(t_);
            t_ = e4.y + er4.y; t_ = t_ > 0.f ? t_ : NEG_SLOPE * t_; w4.y = __expf(t_);
            t_ = e4.z + er4.z; t_ = t_ > 0.f ? t_ : NEG_SLOPE * t_; w4.z = __expf(t_);
            t_ = e4.w + er4.w; t_ = t_ > 0.f ? t_ : NEG_SLOPE * t_; w4.w = __expf(t_);
        }
        // wave-synchronous: same wave writes and reads its slice
        sSp[wv][lane & 1][lane >> 1]    = boff;
        sW2[wv][0][lane & 1][lane >> 1] = w4.x;
        sW2[wv][1][lane & 1][lane >> 1] = w4.y;
        sW2[wv][2][lane & 1][lane >> 1] = w4.z;
        sW2[wv][3][lane & 1][lane >> 1] = w4.w;
        dx += w4.x; dy += w4.y; dz += w4.z; dw += w4.w;

        // ---- consume: 4 pairs (8 edges) per group, no conditionals ----
        const int pr = ((m + 7) & ~7) >> 1;     // pairs, multiple of 4
        for (int p = 0; p < pr; p += 4) {
            const int4   sa = *(const int4*)(&sSp[wv][half][p]);
            const float4 wa = *(const float4*)(&sW2[wv][h][half][p]);

            uint2 u0 = ld_u64(fb, (unsigned int)sa.x + lane8);
            uint2 u1 = ld_u64(fb, (unsigned int)sa.y + lane8);
            uint2 u2 = ld_u64(fb, (unsigned int)sa.z + lane8);
            uint2 u3 = ld_u64(fb, (unsigned int)sa.w + lane8);

            a0 += wa.x * __uint_as_float(u0.x << 16);
            a1 += wa.x * __uint_as_float(u0.x & 0xFFFF0000u);
            a2 += wa.x * __uint_as_float(u0.y << 16);
            a3 += wa.x * __uint_as_float(u0.y & 0xFFFF0000u);
            a0 += wa.y * __uint_as_float(u1.x << 16);
            a1 += wa.y * __uint_as_float(u1.x & 0xFFFF0000u);
            a2 += wa.y * __uint_as_float(u1.y << 16);
            a3 += wa.y * __uint_as_float(u1.y & 0xFFFF0000u);
            a0 += wa.z * __uint_as_float(u2.x << 16);
            a1 += wa.z * __uint_as_float(u2.x & 0xFFFF0000u);
            a2 += wa.z * __uint_as_float(u2.y << 16);
            a3 += wa.z * __uint_as_float(u2.y & 0xFFFF0000u);
            a0 += wa.w * __uint_as_float(u3.x << 16);
            a1 += wa.w * __uint_as_float(u3.x & 0xFFFF0000u);
            a2 += wa.w * __uint_as_float(u3.y << 16);
            a3 += wa.w * __uint_as_float(u3.y & 0xFFFF0000u);
        }
    }

    // merge the two edge-parities: lane s and lane s+32 hold the same features
    a0 += __shfl_xor(a0, 32);
    a1 += __shfl_xor(a1, 32);
    a2 += __shfl_xor(a2, 32);
    a3 += __shfl_xor(a3, 32);

    // den: butterfly-reduce the staged weight sums across all 64 lanes
#pragma unroll
    for (int sh = 1; sh < 64; sh <<= 1) {
        dx += __shfl_xor(dx, sh);
        dy += __shfl_xor(dy, sh);
        dz += __shfl_xor(dz, sh);
        dw += __shfl_xor(dw, sh);
    }
    float den = (h == 0) ? dx : (h == 1) ? dy : (h == 2) ? dz : dw;

    if (lane < 32) {
        float scale = den > 0.f ? 1.f / den : 0.f;
        float o0 = a0 * scale, o1 = a1 * scale, o2 = a2 * scale, o3 = a3 * scale;
        size_t ob = (size_t)nd * 128 + sub * 4;     // ushort index, 8B aligned
        if (resb) {
            uint2 rv = *(const uint2*)(resb + ob);
            o0 += __uint_as_float(rv.x << 16);
            o1 += __uint_as_float(rv.x & 0xFFFF0000u);
            o2 += __uint_as_float(rv.y << 16);
            o3 += __uint_as_float(rv.y & 0xFFFF0000u);
        }
        o0 = fmaxf(o0, 0.f);
        o1 = fmaxf(o1, 0.f);
        o2 = fmaxf(o2, 0.f);
        o3 = fmaxf(o3, 0.f);
        uint2 ou;
        ou.x = (unsigned int)f2bf(o0) | ((unsigned int)f2bf(o1) << 16);
        ou.y = (unsigned int)f2bf(o2) | ((unsigned int)f2bf(o3) << 16);
        *(uint2*)(outb + ob) = ou;
    }
}

// ---------------------------------------------------------------------------
// Pull aggregation, H=1, C=16: wave per node, LDS staging, 8 edge-groups of
// 8 lanes; lane owns a feature pair. Final output f32 (+res2).
// sorted_boff holds src*256; feat2b byte = boff>>3, el byte = boff>>6.
// ---------------------------------------------------------------------------
__global__ __launch_bounds__(256) void gat_agg16(const int* __restrict__ rowptr,
                                                 const int* __restrict__ deg,
                                                 const int* __restrict__ sorted_boff,
                                                 const float* __restrict__ el,
                                                 const float* __restrict__ er,
                                                 const unsigned short* __restrict__ feat2b,
                                                 const float* __restrict__ res,
                                                 float* __restrict__ out) {
    __shared__ int   sS[4][64];
    __shared__ float sW[4][64];

    const int wv   = threadIdx.x >> 6;
    const int lane = threadIdx.x & 63;
    const int nd   = blockIdx.x * 4 + (threadIdx.x >> 6);
    const int g    = lane >> 3;
    const unsigned int flane4 = (unsigned int)((lane & 7) << 2);
    const char* f2base = (const char*)feat2b;
    const char* eb = (const char*)el;

    const int dg = deg[nd];
    const int r0 = rowptr[nd];
    const float erd = er[nd];

    float ax = 0.f, ay = 0.f, den = 0.f;

    for (int base = 0; base < dg; base += 64) {
        int m = dg - base; if (m > 64) m = 64;
        if (lane < m) {
            int boff = sorted_boff[r0 + base + lane];
            sS[wv][lane] = boff;
            float v = *(const float*)(eb + (unsigned int)(boff >> 6)) + erd;
            v = v > 0.f ? v : NEG_SLOPE * v;
            sW[wv][lane] = __expf(v);
        }
        for (int i = g; i < m; i += 8) {
            int bo  = sS[wv][i];
            float w = sW[wv][i];
            den += w;
            unsigned int u = *(const unsigned int*)(f2base + (unsigned int)(bo >> 3) + flane4);
            ax += w * __uint_as_float(u << 16);
            ay += w * __uint_as_float(u & 0xFFFF0000u);
        }
    }

    ax += __shfl_down(ax, 32); ay += __shfl_down(ay, 32); den += __shfl_down(den, 32);
    ax += __shfl_down(ax, 16); ay += __shfl_down(ay, 16); den += __shfl_down(den, 16);
    ax += __shfl_down(ax, 8);  ay += __shfl_down(ay, 8);  den += __shfl_down(den, 8);

    if (lane < 8) {
        float scale = den > 0.f ? 1.f / den : 0.f;
        size_t o0 = (size_t)nd * 16 + ((lane & 7) << 1);
        float2 o;
        o.x = ax * scale + res[o0];
        o.y = ay * scale + res[o0 + 1];
        *(float2*)(out + o0) = o;
    }
}

// ---------------------------------------------------------------------------
extern "C" void kernel_launch(void* const* d_in, const int* in_sizes, int n_in,
                              void* d_out, int out_size, void* d_ws, size_t ws_size,
                              hipStream_t stream) {
    const float* inputs = (const float*)d_in[0];
    const int*   src    = (const int*)d_in[1];
    const int*   dst    = (const int*)d_in[2];
    const float* W0     = (const float*)d_in[3];
    const float* al0    = (const float*)d_in[4];
    const float* ar0    = (const float*)d_in[5];
    const float* W1     = (const float*)d_in[6];
    const float* al1    = (const float*)d_in[7];
    const float* ar1    = (const float*)d_in[8];
    const float* W2     = (const float*)d_in[9];
    const float* al2    = (const float*)d_in[10];
    const float* ar2    = (const float*)d_in[11];
    const float* resW2  = (const float*)d_in[12];
    float* out = (float*)d_out;

    const size_t NF = (size_t)N_NODES * 128;
    float* ws   = (float*)d_ws;
    float* el   = ws;                                  // N*4
    float* er   = el + (size_t)N_NODES * 4;            // N*4
    float* res2 = er + (size_t)N_NODES * 4;            // N*16
    unsigned short* hbufb  = (unsigned short*)(res2 + (size_t)N_NODES * 16);  // N*128 bf16
    unsigned short* featb  = hbufb + NF;               // N*128 bf16
    unsigned short* feat2b = featb + NF;               // N*16 bf16
    unsigned short* W0p    = feat2b + (size_t)N_NODES * 16;  // 16384
    unsigned short* W1p    = W0p + 16384;                    // 16384
    unsigned short* W2p    = W1p + 16384;                    // 8192
    int* iws = (int*)(W2p + 8192);
    unsigned int* pe = (unsigned int*)iws;             // NBUCK*BCAP padded
    int* sorted_boff = iws + NBUCK * BCAP;             // NBUCK*BCAP padded
    int* deg         = sorted_boff + NBUCK * BCAP;     // N
    int* rowptr      = deg + N_NODES;                  // N
    int* bcursor     = rowptr + N_NODES;               // 512

    dim3 blk(256);
    int aggGrid = N_NODES / 4;                         // 25000

    // ---- K1: cursor init + weight pack ----
    init_pack<<<162, blk, 0, stream>>>(bcursor, W0, W1, W2, resW2, W0p, W1p, W2p);
    // ---- K2: partition + layer-0 GEMM ----
    part_gemm0<<<PGRID + GEMMGRID, blk, 0, stream>>>(src, dst, bcursor, pe, N_EDGES,
                                                     inputs, W0p, al0, ar0, featb,
                                                     el, er, N_NODES);
    // ---- K3: finalize CSR ----
    bucket_finalize<<<PGRID, blk, 0, stream>>>(pe, bcursor, rowptr, deg, sorted_boff);

    // ---- layer 0 aggregation ----
    gat_agg128<<<aggGrid, blk, 0, stream>>>(rowptr, deg, sorted_boff, el, er, featb,
                                            nullptr, hbufb);

    // ---- layer 1 ----
    gemm128_mfma_bf16<<<GEMMGRID, blk, 0, stream>>>(hbufb, W1p, al1, ar1, featb,
                                                    el, er, N_NODES);
    gat_agg128<<<aggGrid, blk, 0, stream>>>(rowptr, deg, sorted_boff, el, er, featb,
                                            hbufb, hbufb);

    // ---- layer 2 ----
    gemm16_mfma<<<GEMMGRID, blk, 0, stream>>>(hbufb, W2p, al2, ar2, feat2b, res2,
                                              el, er, N_NODES);
    gat_agg16<<<aggGrid, blk, 0, stream>>>(rowptr, deg, sorted_boff, el, er, feat2b,
                                           res2, out);
}

// Round 6
// 383.556 us; speedup vs baseline: 1.0925x; 1.0046x over previous
//
#include <hip/hip_runtime.h>

#define N_NODES 100000
#define N_EDGES 1600000
#define IN_F    128
#define NEG_SLOPE 0.2f
#define NBUCK   512                 // bucket = dst>>8; 391 active
#define BCAP    5120                // padded bucket capacity (mean 4096, +16 sigma)
#define PCHUNK  4096                // edges per partition block
#define PGRID   391                 // ceil(N_EDGES / PCHUNK)
#define GEMMGRID 1563               // ceil(N_NODES / 64)

typedef __attribute__((ext_vector_type(8))) short bf16x8;
typedef __attribute__((ext_vector_type(4))) float f32x4;

__device__ __forceinline__ float bf2f(unsigned short u) {
    return __uint_as_float(((unsigned int)u) << 16);
}

// f32 -> bf16 round-to-nearest-even
__device__ __forceinline__ unsigned short f2bf(float f) {
    unsigned int u = __float_as_uint(f);
    u += 0x7FFFu + ((u >> 16) & 1u);
    return (unsigned short)(u >> 16);
}

// uniform-base + 32-bit-offset loads: encourage global_load saddr form
__device__ __forceinline__ unsigned int ld_u32(const char* base, unsigned int off) {
    return *(const unsigned int*)(base + off);
}
__device__ __forceinline__ uint2 ld_u64(const char* base, unsigned int off) {
    return *(const uint2*)(base + off);
}

// ---------------------------------------------------------------------------
// K1: cursor init (blocks 0..1) + weight pack (blocks 2..161) + folded
// attention-vector pack (blocks 162..164).
// Pack layout: Wp[((nt*4+kt)*64+lane)*8+j] = W[kt*32+(lane>>4)*8+j][nt*16+(lane&15)]
// Walp: 128x16 tile, cols 0..3 = W@al per head, cols 4..7 = W@ar, rest 0.
// Walp2: col 0 = W2@al2, col 1 = W2@ar2, rest 0.
// el/er then come out of one extra MFMA in the GEMMs (el = A@(W@al)),
// deleting the 128-shfl epilogue reductions.
// ---------------------------------------------------------------------------
__global__ __launch_bounds__(256) void init_pack(int* __restrict__ bcursor,
                                                 const float* __restrict__ W0,
                                                 const float* __restrict__ W1,
                                                 const float* __restrict__ W2,
                                                 const float* __restrict__ rW2,
                                                 unsigned short* __restrict__ W0p,
                                                 unsigned short* __restrict__ W1p,
                                                 unsigned short* __restrict__ W2p,
                                                 const float* __restrict__ al0,
                                                 const float* __restrict__ ar0,
                                                 const float* __restrict__ al1,
                                                 const float* __restrict__ ar1,
                                                 const float* __restrict__ al2,
                                                 const float* __restrict__ ar2,
                                                 unsigned short* __restrict__ Walp0,
                                                 unsigned short* __restrict__ Walp1,
                                                 unsigned short* __restrict__ Walp2) {
    const int t = threadIdx.x;
    if (blockIdx.x < 2) {
        int i = blockIdx.x * 256 + t;
        if (i < NBUCK) bcursor[i] = i * BCAP;
        return;
    }
    if (blockIdx.x < 162) {
        int gid = (blockIdx.x - 2) * 256 + t;            // < 40960
        const float* W;
        unsigned short* Wp;
        int idx, ncols;
        if (gid < 16384)      { W = W0; Wp = W0p; idx = gid;          ncols = 128; }
        else if (gid < 32768) { W = W1; Wp = W1p; idx = gid - 16384;  ncols = 128; }
        else                  { W = W2; Wp = W2p; idx = gid - 32768;  ncols = 32;  }
        int j  = idx & 7;
        int l  = (idx >> 3) & 63;
        int kt = (idx >> 9) & 3;
        int nt = idx >> 11;
        int k  = kt * 32 + (l >> 4) * 8 + j;
        int n  = nt * 16 + (l & 15);
        float v;
        if (ncols == 128) v = W[k * 128 + n];
        else              v = (n < 16) ? W[k * 16 + n] : rW2[k * 16 + (n - 16)];
        Wp[idx] = f2bf(v);
        return;
    }
    // ---- folded al/ar packs ----
    if (blockIdx.x < 164) {
        const float* W  = (blockIdx.x == 162) ? W0 : W1;
        const float* al = (blockIdx.x == 162) ? al0 : al1;
        const float* ar = (blockIdx.x == 162) ? ar0 : ar1;
        unsigned short* Wa = (blockIdx.x == 162) ? Walp0 : Walp1;
        for (int e = t; e < 2048; e += 256) {
            int k = e >> 4, c = e & 15;
            float s = 0.f;
            if (c < 8) {
                int h = c & 3;
                const float* av = (c < 4) ? al : ar;
                const float* wr = W + k * 128 + h * 32;
#pragma unroll
                for (int d = 0; d < 32; ++d) s += wr[d] * av[h * 32 + d];
            }
            int kt = k >> 5, rem = k & 31;
            int lane = (rem >> 3) * 16 + c, j = rem & 7;
            Wa[(kt * 64 + lane) * 8 + j] = f2bf(s);
        }
        return;
    }
    // block 164: layer-2 fold (cols 0=W2@al2, 1=W2@ar2)
    for (int e = t; e < 2048; e += 256) {
        int k = e >> 4, c = e & 15;
        float s = 0.f;
        if (c < 2) {
            const float* av = (c == 0) ? al2 : ar2;
#pragma unroll
            for (int cc = 0; cc < 16; ++cc) s += W2[k * 16 + cc] * av[cc];
        }
        int kt = k >> 5, rem = k & 31;
        int lane = (rem >> 3) * 16 + c, j = rem & 7;
        Walp2[(kt * 64 + lane) * 8 + j] = f2bf(s);
    }
}

// ---------------------------------------------------------------------------
// K2: edge partition into padded buckets (blocks [0,PGRID)) + layer-0 MFMA
// GEMM (blocks [PGRID, PGRID+GEMMGRID)), el/er via folded Walp MFMA.
// ---------------------------------------------------------------------------
__global__ __launch_bounds__(256) void part_gemm0(const int* __restrict__ src,
                                                  const int* __restrict__ dst,
                                                  int* __restrict__ bcursor,
                                                  unsigned int* __restrict__ pe, int nE,
                                                  const float* __restrict__ A,
                                                  const unsigned short* __restrict__ Wp,
                                                  const unsigned short* __restrict__ Walp,
                                                  unsigned short* __restrict__ featb,
                                                  float* __restrict__ el,
                                                  float* __restrict__ er,
                                                  int nrows) {
    __shared__ int hist[NBUCK];
    __shared__ int lstart[NBUCK];
    __shared__ int gbase[NBUCK];
    __shared__ int curB[NBUCK];
    __shared__ int s[NBUCK];
    __shared__ unsigned int reorder[PCHUNK];

    const int t = threadIdx.x;

    if (blockIdx.x < PGRID) {
        const int start = blockIdx.x * PCHUNK;

        hist[t] = 0; hist[t + 256] = 0;
        __syncthreads();
#pragma unroll
        for (int j = 0; j < PCHUNK / 256; ++j) {
            int e = start + j * 256 + t;
            if (e < nE) atomicAdd(&hist[dst[e] >> 8], 1);
        }
        __syncthreads();
        const int c0 = hist[t];
        const int c1 = hist[t + 256];
        s[t] = c0; s[t + 256] = c1;
        __syncthreads();
        // 512-wide inclusive scan with 256 threads
#pragma unroll
        for (int off = 1; off <= 256; off <<= 1) {
            int x0 = (t >= off) ? s[t - off] : 0;
            int x1 = s[t + 256 - off];
            __syncthreads();
            s[t] += x0; s[t + 256] += x1;
            __syncthreads();
        }
        lstart[t]       = s[t] - c0;
        lstart[t + 256] = s[t + 256] - c1;
        curB[t]         = s[t] - c0;
        curB[t + 256]   = s[t + 256] - c1;
        gbase[t]        = c0 ? atomicAdd(&bcursor[t],       c0) : 0;
        gbase[t + 256]  = c1 ? atomicAdd(&bcursor[t + 256], c1) : 0;
        __syncthreads();

#pragma unroll
        for (int j = 0; j < PCHUNK / 256; ++j) {
            int e = start + j * 256 + t;
            if (e < nE) {
                int d  = dst[e];
                int sv = src[e];
                int b  = d >> 8;
                int pos = atomicAdd(&curB[b], 1);
                reorder[pos] = ((unsigned)sv << 8) | ((unsigned)d & 255u);
            }
        }
        __syncthreads();

        // flush: one thread per bucket writes its contiguous run
        for (int b = t; b < NBUCK; b += 256) {
            int st = lstart[b];
            int en = curB[b];
            int gb = gbase[b];
            for (int k = st; k < en; ++k)
                pe[gb + (k - st)] = reorder[k];
        }
    } else {
        // ---------------- layer-0 GEMM ----------------
        const int bid  = blockIdx.x - PGRID;
        const int wv   = t >> 6;
        const int lane = t & 63;
        const int q    = lane >> 4;
        const int m    = lane & 15;
        const int rb   = bid * 64 + wv * 16;
        const int arow = rb + m;
        const bool rok = arow < nrows;
        const float* Ar = A + (size_t)arow * IN_F;

        f32x4 acc[8];
#pragma unroll
        for (int nt = 0; nt < 8; ++nt) acc[nt] = (f32x4){0.f, 0.f, 0.f, 0.f};
        f32x4 acc_a = (f32x4){0.f, 0.f, 0.f, 0.f};

#pragma unroll
        for (int kt = 0; kt < 4; ++kt) {
            bf16x8 afr = (bf16x8){0, 0, 0, 0, 0, 0, 0, 0};
            if (rok) {
                float4 v0 = *(const float4*)(Ar + kt * 32 + q * 8);
                float4 v1 = *(const float4*)(Ar + kt * 32 + q * 8 + 4);
                afr[0] = (short)f2bf(v0.x); afr[1] = (short)f2bf(v0.y);
                afr[2] = (short)f2bf(v0.z); afr[3] = (short)f2bf(v0.w);
                afr[4] = (short)f2bf(v1.x); afr[5] = (short)f2bf(v1.y);
                afr[6] = (short)f2bf(v1.z); afr[7] = (short)f2bf(v1.w);
            }
#pragma unroll
            for (int nt = 0; nt < 8; ++nt) {
                bf16x8 bfr = *(const bf16x8*)(Wp + ((size_t)(nt * 4 + kt) * 64 + lane) * 8);
                acc[nt] = __builtin_amdgcn_mfma_f32_16x16x32_bf16(afr, bfr, acc[nt], 0, 0, 0);
            }
            bf16x8 wfr = *(const bf16x8*)(Walp + ((size_t)kt * 64 + lane) * 8);
            acc_a = __builtin_amdgcn_mfma_f32_16x16x32_bf16(afr, wfr, acc_a, 0, 0, 0);
        }

#pragma unroll
        for (int nt = 0; nt < 8; ++nt) {
            const int col = nt * 16 + m;
#pragma unroll
            for (int reg = 0; reg < 4; ++reg) {
                int row = rb + q * 4 + reg;
                if (row < nrows) featb[(size_t)row * 128 + col] = f2bf(acc[nt][reg]);
            }
        }
        if (m < 8) {
            float* dstp = (m < 4) ? el : er;
            const int hh = m & 3;
#pragma unroll
            for (int reg = 0; reg < 4; ++reg) {
                int row = rb + q * 4 + reg;
                if (row < nrows) dstp[row * 4 + hh] = acc_a[reg];
            }
        }
    }
}

// ---------------------------------------------------------------------------
// K3: per-bucket finalize — degree histogram + local scan -> rowptr/deg,
// within-bucket sort -> sorted_boff (BYTE offsets src*256, = ed & ~255).
// ---------------------------------------------------------------------------
__global__ __launch_bounds__(256) void bucket_finalize(const unsigned int* __restrict__ pe,
                                                       const int* __restrict__ bcursor,
                                                       int* __restrict__ rowptr,
                                                       int* __restrict__ deg,
                                                       int* __restrict__ sorted_boff) {
    __shared__ int deg_l[256];
    __shared__ int s[256];
    __shared__ int cur[256];

    const int b  = blockIdx.x;
    const int t  = threadIdx.x;
    const int base = b * BCAP;
    const int cnt  = bcursor[b] - base;
    const int n    = b * 256 + t;

    deg_l[t] = 0;
    __syncthreads();
    for (int i = t; i < cnt; i += 256)
        atomicAdd(&deg_l[pe[base + i] & 255u], 1);
    __syncthreads();

    const int dv = deg_l[t];
    s[t] = dv;
    __syncthreads();
#pragma unroll
    for (int off = 1; off < 256; off <<= 1) {
        int x = (t >= off) ? s[t - off] : 0;
        __syncthreads();
        s[t] += x;
        __syncthreads();
    }
    const int off_l = s[t] - dv;
    if (n < N_NODES) {
        rowptr[n] = base + off_l;
        deg[n]    = dv;
    }
    cur[t] = off_l;
    __syncthreads();

    for (int i = t; i < cnt; i += 256) {
        unsigned int ed = pe[base + i];
        int pos = atomicAdd(&cur[ed & 255u], 1);
        sorted_boff[base + pos] = (int)(ed & 0xFFFFFF00u);   // src*256 byte offset
    }
}

// ---------------------------------------------------------------------------
// MFMA GEMM, bf16 A (layer 1): featb = Ab @ Wp; el/er via folded Walp MFMA.
// ---------------------------------------------------------------------------
__global__ __launch_bounds__(256) void gemm128_mfma_bf16(const unsigned short* __restrict__ Ab,
                                                         const unsigned short* __restrict__ Wp,
                                                         const unsigned short* __restrict__ Walp,
                                                         unsigned short* __restrict__ featb,
                                                         float* __restrict__ el,
                                                         float* __restrict__ er,
                                                         int nrows) {
    const int t    = threadIdx.x;
    const int wv   = t >> 6;
    const int lane = t & 63;
    const int q    = lane >> 4;
    const int m    = lane & 15;
    const int rb   = blockIdx.x * 64 + wv * 16;
    const int arow = rb + m;
    const bool rok = arow < nrows;
    const unsigned short* Ar = Ab + (size_t)arow * IN_F;

    f32x4 acc[8];
#pragma unroll
    for (int nt = 0; nt < 8; ++nt) acc[nt] = (f32x4){0.f, 0.f, 0.f, 0.f};
    f32x4 acc_a = (f32x4){0.f, 0.f, 0.f, 0.f};

#pragma unroll
    for (int kt = 0; kt < 4; ++kt) {
        bf16x8 afr = (bf16x8){0, 0, 0, 0, 0, 0, 0, 0};
        if (rok) afr = *(const bf16x8*)(Ar + kt * 32 + q * 8);
#pragma unroll
        for (int nt = 0; nt < 8; ++nt) {
            bf16x8 bfr = *(const bf16x8*)(Wp + ((size_t)(nt * 4 + kt) * 64 + lane) * 8);
            acc[nt] = __builtin_amdgcn_mfma_f32_16x16x32_bf16(afr, bfr, acc[nt], 0, 0, 0);
        }
        bf16x8 wfr = *(const bf16x8*)(Walp + ((size_t)kt * 64 + lane) * 8);
        acc_a = __builtin_amdgcn_mfma_f32_16x16x32_bf16(afr, wfr, acc_a, 0, 0, 0);
    }

#pragma unroll
    for (int nt = 0; nt < 8; ++nt) {
        const int col = nt * 16 + m;
#pragma unroll
        for (int reg = 0; reg < 4; ++reg) {
            int row = rb + q * 4 + reg;
            if (row < nrows) featb[(size_t)row * 128 + col] = f2bf(acc[nt][reg]);
        }
    }
    if (m < 8) {
        float* dstp = (m < 4) ? el : er;
        const int hh = m & 3;
#pragma unroll
        for (int reg = 0; reg < 4; ++reg) {
            int row = rb + q * 4 + reg;
            if (row < nrows) dstp[row * 4 + hh] = acc_a[reg];
        }
    }
}

// ---------------------------------------------------------------------------
// MFMA dual GEMM layer 2 (bf16 A): [feat2b(bf16) | res2(f32)] = A @ [W2|resW2];
// el/er via folded Walp2 MFMA (cols 0/1).
// ---------------------------------------------------------------------------
__global__ __launch_bounds__(256) void gemm16_mfma(const unsigned short* __restrict__ Ab,
                                                   const unsigned short* __restrict__ Wp,
                                                   const unsigned short* __restrict__ Walp,
                                                   unsigned short* __restrict__ feat2b,
                                                   float* __restrict__ res2,
                                                   float* __restrict__ el,
                                                   float* __restrict__ er,
                                                   int nrows) {
    const int t    = threadIdx.x;
    const int wv   = t >> 6;
    const int lane = t & 63;
    const int q    = lane >> 4;
    const int m    = lane & 15;
    const int rb   = blockIdx.x * 64 + wv * 16;
    const int arow = rb + m;
    const bool rok = arow < nrows;
    const unsigned short* Ar = Ab + (size_t)arow * IN_F;

    f32x4 acc0 = (f32x4){0.f, 0.f, 0.f, 0.f};
    f32x4 acc1 = (f32x4){0.f, 0.f, 0.f, 0.f};
    f32x4 acc_a = (f32x4){0.f, 0.f, 0.f, 0.f};

#pragma unroll
    for (int kt = 0; kt < 4; ++kt) {
        bf16x8 afr = (bf16x8){0, 0, 0, 0, 0, 0, 0, 0};
        if (rok) afr = *(const bf16x8*)(Ar + kt * 32 + q * 8);
        bf16x8 b0 = *(const bf16x8*)(Wp + ((size_t)(0 * 4 + kt) * 64 + lane) * 8);
        bf16x8 b1 = *(const bf16x8*)(Wp + ((size_t)(1 * 4 + kt) * 64 + lane) * 8);
        acc0 = __builtin_amdgcn_mfma_f32_16x16x32_bf16(afr, b0, acc0, 0, 0, 0);
        acc1 = __builtin_amdgcn_mfma_f32_16x16x32_bf16(afr, b1, acc1, 0, 0, 0);
        bf16x8 wfr = *(const bf16x8*)(Walp + ((size_t)kt * 64 + lane) * 8);
        acc_a = __builtin_amdgcn_mfma_f32_16x16x32_bf16(afr, wfr, acc_a, 0, 0, 0);
    }

#pragma unroll
    for (int reg = 0; reg < 4; ++reg) {
        int row = rb + q * 4 + reg;
        if (row < nrows) {
            feat2b[(size_t)row * 16 + m] = f2bf(acc0[reg]);
            res2[(size_t)row * 16 + m]   = acc1[reg];
        }
    }
    if (m < 2) {
        float* dstp = (m == 0) ? el : er;
#pragma unroll
        for (int reg = 0; reg < 4; ++reg) {
            int row = rb + q * 4 + reg;
            if (row < nrows) dstp[row] = acc_a[reg];
        }
    }
}

// ---------------------------------------------------------------------------
// Pull aggregation, H=4, D=32, bf16 gathers, wave per node, bf16 in/out.
// (v3-exact: the known-best 74.0 µs form; 6 variants showed this kernel is
// at the random-gather fabric plateau — FETCH invariant at the 8-XCD floor.)
// ---------------------------------------------------------------------------
__global__ __launch_bounds__(256) void gat_agg128(const int* __restrict__ rowptr,
                                                  const int* __restrict__ deg,
                                                  const int* __restrict__ sorted_boff,
                                                  const float* __restrict__ el,
                                                  const float* __restrict__ er,
                                                  const unsigned short* __restrict__ featb,
                                                  const unsigned short* __restrict__ resb,
                                                  unsigned short* __restrict__ outb) {
    __shared__ __align__(16) int   sS[4][64];
    __shared__ __align__(16) float sW[4][4][68];

    const int wv   = threadIdx.x >> 6;
    const int lane = threadIdx.x & 63;
    const int nd   = blockIdx.x * 4 + wv;

    const int dg = deg[nd];
    const int r0 = rowptr[nd];
    const int h  = lane >> 4;
    const unsigned int lane4 = (unsigned int)(lane << 2);
    const float4 er4 = *(const float4*)(er + nd * 4);
    const char* fb = (const char*)featb;
    const char* eb = (const char*)el;

    float dx = 0.f, dy = 0.f, dz = 0.f, dw = 0.f;
    float ax = 0.f, ay = 0.f;

    for (int base = 0; base < dg; base += 64) {
        int m = dg - base; if (m > 64) m = 64;

        // ---- stage: each lane owns one edge ----
        int boff = 0;
        float4 w4 = {0.f, 0.f, 0.f, 0.f};
        if (lane < m) {
            boff = sorted_boff[r0 + base + lane];
            float4 e4 = *(const float4*)(eb + (unsigned int)(boff >> 4));
            float t_;
            t_ = e4.x + er4.x; t_ = t_ > 0.f ? t_ : NEG_SLOPE * t_; w4.x = __expf(t_);
            t_ = e4.y + er4.y; t_ = t_ > 0.f ? t_ : NEG_SLOPE * t_; w4.y = __expf(t_);
            t_ = e4.z + er4.z; t_ = t_ > 0.f ? t_ : NEG_SLOPE * t_; w4.z = __expf(t_);
            t_ = e4.w + er4.w; t_ = t_ > 0.f ? t_ : NEG_SLOPE * t_; w4.w = __expf(t_);
        }
        // wave-synchronous: same wave writes and reads its slice
        sS[wv][lane]    = boff;
        sW[wv][0][lane] = w4.x;
        sW[wv][1][lane] = w4.y;
        sW[wv][2][lane] = w4.z;
        sW[wv][3][lane] = w4.w;
        dx += w4.x; dy += w4.y; dz += w4.z; dw += w4.w;

        // ---- consume: 8 edges per group, no conditionals ----
        const int mr = (m + 7) & ~7;
        for (int i = 0; i < mr; i += 8) {
            const int4   sa = *(const int4*)(&sS[wv][i]);
            const int4   sb = *(const int4*)(&sS[wv][i + 4]);
            const float4 wa = *(const float4*)(&sW[wv][h][i]);
            const float4 wb = *(const float4*)(&sW[wv][h][i + 4]);

            unsigned int u0 = ld_u32(fb, (unsigned int)sa.x + lane4);
            unsigned int u1 = ld_u32(fb, (unsigned int)sa.y + lane4);
            unsigned int u2 = ld_u32(fb, (unsigned int)sa.z + lane4);
            unsigned int u3 = ld_u32(fb, (unsigned int)sa.w + lane4);
            unsigned int u4 = ld_u32(fb, (unsigned int)sb.x + lane4);
            unsigned int u5 = ld_u32(fb, (unsigned int)sb.y + lane4);
            unsigned int u6 = ld_u32(fb, (unsigned int)sb.z + lane4);
            unsigned int u7 = ld_u32(fb, (unsigned int)sb.w + lane4);

            ax += wa.x * __uint_as_float(u0 << 16);
            ay += wa.x * __uint_as_float(u0 & 0xFFFF0000u);
            ax += wa.y * __uint_as_float(u1 << 16);
            ay += wa.y * __uint_as_float(u1 & 0xFFFF0000u);
            ax += wa.z * __uint_as_float(u2 << 16);
            ay += wa.z * __uint_as_float(u2 & 0xFFFF0000u);
            ax += wa.w * __uint_as_float(u3 << 16);
            ay += wa.w * __uint_as_float(u3 & 0xFFFF0000u);
            ax += wb.x * __uint_as_float(u4 << 16);
            ay += wb.x * __uint_as_float(u4 & 0xFFFF0000u);
            ax += wb.y * __uint_as_float(u5 << 16);
            ay += wb.y * __uint_as_float(u5 & 0xFFFF0000u);
            ax += wb.z * __uint_as_float(u6 << 16);
            ay += wb.z * __uint_as_float(u6 & 0xFFFF0000u);
            ax += wb.w * __uint_as_float(u7 << 16);
            ay += wb.w * __uint_as_float(u7 & 0xFFFF0000u);
        }
    }

    // den: butterfly-reduce the staged weight sums across all 64 lanes
#pragma unroll
    for (int sh = 1; sh < 64; sh <<= 1) {
        dx += __shfl_xor(dx, sh);
        dy += __shfl_xor(dy, sh);
        dz += __shfl_xor(dz, sh);
        dw += __shfl_xor(dw, sh);
    }
    float den = (h == 0) ? dx : (h == 1) ? dy : (h == 2) ? dz : dw;

    float scale = den > 0.f ? 1.f / den : 0.f;
    float ox = ax * scale, oy = ay * scale;
    size_t o0 = (size_t)nd * 128 + lane * 2;
    if (resb) {
        ushort2 rv = *(const ushort2*)(resb + o0);
        ox += bf2f(rv.x);
        oy += bf2f(rv.y);
    }
    ox = fmaxf(ox, 0.f);
    oy = fmaxf(oy, 0.f);
    ushort2 ou;
    ou.x = f2bf(ox);
    ou.y = f2bf(oy);
    *(ushort2*)(outb + o0) = ou;
}

// ---------------------------------------------------------------------------
// Pull aggregation, H=1, C=16: wave per node; v7: 4 lanes per edge (16 edges
// in flight, was 8x8), ld_u64 feature reads (4 features/lane), xor-tree
// reduce, float4 output. Halves per-edge instruction count.
// sorted_boff holds src*256; feat2b byte = boff>>3, el byte = boff>>6.
// ---------------------------------------------------------------------------
__global__ __launch_bounds__(256) void gat_agg16(const int* __restrict__ rowptr,
                                                 const int* __restrict__ deg,
                                                 const int* __restrict__ sorted_boff,
                                                 const float* __restrict__ el,
                                                 const float* __restrict__ er,
                                                 const unsigned short* __restrict__ feat2b,
                                                 const float* __restrict__ res,
                                                 float* __restrict__ out) {
    __shared__ int   sS[4][64];
    __shared__ float sW[4][64];

    const int wv   = threadIdx.x >> 6;
    const int lane = threadIdx.x & 63;
    const int nd   = blockIdx.x * 4 + wv;
    const int grp  = lane >> 2;                              // 16 edge groups
    const unsigned int fo = (unsigned int)((lane & 3) << 3); // 8B of the 32B row
    const char* f2base = (const char*)feat2b;
    const char* eb = (const char*)el;

    const int dg = deg[nd];
    const int r0 = rowptr[nd];
    const float erd = er[nd];

    float a0 = 0.f, a1 = 0.f, a2 = 0.f, a3 = 0.f, den = 0.f;

    for (int base = 0; base < dg; base += 64) {
        int m = dg - base; if (m > 64) m = 64;
        if (lane < m) {
            int boff = sorted_boff[r0 + base + lane];
            sS[wv][lane] = boff;
            float v = *(const float*)(eb + (unsigned int)(boff >> 6)) + erd;
            v = v > 0.f ? v : NEG_SLOPE * v;
            sW[wv][lane] = __expf(v);
        }
        for (int i = grp; i < m; i += 16) {
            int bo  = sS[wv][i];
            float w = sW[wv][i];
            den += w;
            uint2 u = ld_u64(f2base, (unsigned int)(bo >> 3) + fo);
            a0 += w * __uint_as_float(u.x << 16);
            a1 += w * __uint_as_float(u.x & 0xFFFF0000u);
            a2 += w * __uint_as_float(u.y << 16);
            a3 += w * __uint_as_float(u.y & 0xFFFF0000u);
        }
    }

    // reduce over the 16 groups (lanes sharing lane&3)
#pragma unroll
    for (int sh = 4; sh < 64; sh <<= 1) {
        a0 += __shfl_xor(a0, sh);
        a1 += __shfl_xor(a1, sh);
        a2 += __shfl_xor(a2, sh);
        a3 += __shfl_xor(a3, sh);
        den += __shfl_xor(den, sh);
    }

    if (lane < 4) {
        float scale = den > 0.f ? 1.f / den : 0.f;
        size_t ob = (size_t)nd * 16 + lane * 4;
        float4 o;
        o.x = a0 * scale + res[ob];
        o.y = a1 * scale + res[ob + 1];
        o.z = a2 * scale + res[ob + 2];
        o.w = a3 * scale + res[ob + 3];
        *(float4*)(out + ob) = o;
    }
}

// ---------------------------------------------------------------------------
extern "C" void kernel_launch(void* const* d_in, const int* in_sizes, int n_in,
                              void* d_out, int out_size, void* d_ws, size_t ws_size,
                              hipStream_t stream) {
    const float* inputs = (const float*)d_in[0];
    const int*   src    = (const int*)d_in[1];
    const int*   dst    = (const int*)d_in[2];
    const float* W0     = (const float*)d_in[3];
    const float* al0    = (const float*)d_in[4];
    const float* ar0    = (const float*)d_in[5];
    const float* W1     = (const float*)d_in[6];
    const float* al1    = (const float*)d_in[7];
    const float* ar1    = (const float*)d_in[8];
    const float* W2     = (const float*)d_in[9];
    const float* al2    = (const float*)d_in[10];
    const float* ar2    = (const float*)d_in[11];
    const float* resW2  = (const float*)d_in[12];
    float* out = (float*)d_out;

    const size_t NF = (size_t)N_NODES * 128;
    float* ws   = (float*)d_ws;
    float* el   = ws;                                  // N*4
    float* er   = el + (size_t)N_NODES * 4;            // N*4
    float* res2 = er + (size_t)N_NODES * 4;            // N*16
    unsigned short* hbufb  = (unsigned short*)(res2 + (size_t)N_NODES * 16);  // N*128 bf16
    unsigned short* featb  = hbufb + NF;               // N*128 bf16
    unsigned short* feat2b = featb + NF;               // N*16 bf16
    unsigned short* W0p    = feat2b + (size_t)N_NODES * 16;  // 16384
    unsigned short* W1p    = W0p + 16384;                    // 16384
    unsigned short* W2p    = W1p + 16384;                    // 8192
    unsigned short* Walp0  = W2p + 8192;                     // 2048
    unsigned short* Walp1  = Walp0 + 2048;                   // 2048
    unsigned short* Walp2  = Walp1 + 2048;                   // 2048
    int* iws = (int*)(Walp2 + 2048);
    unsigned int* pe = (unsigned int*)iws;             // NBUCK*BCAP padded
    int* sorted_boff = iws + NBUCK * BCAP;             // NBUCK*BCAP padded
    int* deg         = sorted_boff + NBUCK * BCAP;     // N
    int* rowptr      = deg + N_NODES;                  // N
    int* bcursor     = rowptr + N_NODES;               // 512

    dim3 blk(256);
    int aggGrid = N_NODES / 4;                         // 25000

    // ---- K1: cursor init + weight pack + folded al/ar pack ----
    init_pack<<<165, blk, 0, stream>>>(bcursor, W0, W1, W2, resW2, W0p, W1p, W2p,
                                       al0, ar0, al1, ar1, al2, ar2,
                                       Walp0, Walp1, Walp2);
    // ---- K2: partition + layer-0 GEMM ----
    part_gemm0<<<PGRID + GEMMGRID, blk, 0, stream>>>(src, dst, bcursor, pe, N_EDGES,
                                                     inputs, W0p, Walp0, featb,
                                                     el, er, N_NODES);
    // ---- K3: finalize CSR ----
    bucket_finalize<<<PGRID, blk, 0, stream>>>(pe, bcursor, rowptr, deg, sorted_boff);

    // ---- layer 0 aggregation ----
    gat_agg128<<<aggGrid, blk, 0, stream>>>(rowptr, deg, sorted_boff, el, er, featb,
                                            nullptr, hbufb);

    // ---- layer 1 ----
    gemm128_mfma_bf16<<<GEMMGRID, blk, 0, stream>>>(hbufb, W1p, Walp1, featb,
                                                    el, er, N_NODES);
    gat_agg128<<<aggGrid, blk, 0, stream>>>(rowptr, deg, sorted_boff, el, er, featb,
                                            hbufb, hbufb);

    // ---- layer 2 ----
    gemm16_mfma<<<GEMMGRID, blk, 0, stream>>>(hbufb, W2p, Walp2, feat2b, res2,
                                              el, er, N_NODES);
    gat_agg16<<<aggGrid, blk, 0, stream>>>(rowptr, deg, sorted_boff, el, er, feat2b,
                                           res2, out);
}

// Round 9
// 378.802 us; speedup vs baseline: 1.1062x; 1.0125x over previous
//
#include <hip/hip_runtime.h>

#define N_NODES 100000
#define N_EDGES 1600000
#define IN_F    128
#define NEG_SLOPE 0.2f
#define NBUCK   512                 // bucket = dst>>8; 391 active
#define BCAP    5120                // padded bucket capacity (mean 4096, +16 sigma)
#define PCHUNK  4096                // edges per partition block
#define PGRID   391                 // ceil(N_EDGES / PCHUNK)
#define GEMMGRID 1563               // ceil(N_NODES / 64)

typedef __attribute__((ext_vector_type(8))) short bf16x8;
typedef __attribute__((ext_vector_type(4))) float f32x4;

__device__ __forceinline__ float bf2f(unsigned short u) {
    return __uint_as_float(((unsigned int)u) << 16);
}

// f32 -> bf16 round-to-nearest-even
__device__ __forceinline__ unsigned short f2bf(float f) {
    unsigned int u = __float_as_uint(f);
    u += 0x7FFFu + ((u >> 16) & 1u);
    return (unsigned short)(u >> 16);
}

// uniform-base + 32-bit-offset load: encourages global_load saddr form
__device__ __forceinline__ unsigned int ld_u32(const char* base, unsigned int off) {
    return *(const unsigned int*)(base + off);
}

// ---------------------------------------------------------------------------
// K1: cursor init (blocks 0..1) + weight pack (blocks 2..161).
// Pack layout: Wp[((nt*4+kt)*64+lane)*8+j] = W[kt*32+(lane>>4)*8+j][nt*16+(lane&15)]
// ---------------------------------------------------------------------------
__global__ __launch_bounds__(256) void init_pack(int* __restrict__ bcursor,
                                                 const float* __restrict__ W0,
                                                 const float* __restrict__ W1,
                                                 const float* __restrict__ W2,
                                                 const float* __restrict__ rW2,
                                                 unsigned short* __restrict__ W0p,
                                                 unsigned short* __restrict__ W1p,
                                                 unsigned short* __restrict__ W2p) {
    const int t = threadIdx.x;
    if (blockIdx.x < 2) {
        int i = blockIdx.x * 256 + t;
        if (i < NBUCK) bcursor[i] = i * BCAP;
        return;
    }
    int gid = (blockIdx.x - 2) * 256 + t;            // < 40960
    const float* W;
    unsigned short* Wp;
    int idx, ncols;
    if (gid < 16384)      { W = W0; Wp = W0p; idx = gid;          ncols = 128; }
    else if (gid < 32768) { W = W1; Wp = W1p; idx = gid - 16384;  ncols = 128; }
    else                  { W = W2; Wp = W2p; idx = gid - 32768;  ncols = 32;  }
    int j  = idx & 7;
    int l  = (idx >> 3) & 63;
    int kt = (idx >> 9) & 3;
    int nt = idx >> 11;
    int k  = kt * 32 + (l >> 4) * 8 + j;
    int n  = nt * 16 + (l & 15);
    float v;
    if (ncols == 128) v = W[k * 128 + n];
    else              v = (n < 16) ? W[k * 16 + n] : rW2[k * 16 + (n - 16)];
    Wp[idx] = f2bf(v);
}

// ---------------------------------------------------------------------------
// K2: edge partition into padded buckets (blocks [0,PGRID)) + layer-0 MFMA
// GEMM (blocks [PGRID, PGRID+GEMMGRID)).
// ---------------------------------------------------------------------------
__global__ __launch_bounds__(256) void part_gemm0(const int* __restrict__ src,
                                                  const int* __restrict__ dst,
                                                  int* __restrict__ bcursor,
                                                  unsigned int* __restrict__ pe, int nE,
                                                  const float* __restrict__ A,
                                                  const unsigned short* __restrict__ Wp,
                                                  const float* __restrict__ al,
                                                  const float* __restrict__ ar,
                                                  unsigned short* __restrict__ featb,
                                                  float* __restrict__ el,
                                                  float* __restrict__ er,
                                                  int nrows) {
    __shared__ int hist[NBUCK];
    __shared__ int lstart[NBUCK];
    __shared__ int gbase[NBUCK];
    __shared__ int curB[NBUCK];
    __shared__ int s[NBUCK];
    __shared__ unsigned int reorder[PCHUNK];

    const int t = threadIdx.x;

    if (blockIdx.x < PGRID) {
        const int start = blockIdx.x * PCHUNK;

        hist[t] = 0; hist[t + 256] = 0;
        __syncthreads();
#pragma unroll
        for (int j = 0; j < PCHUNK / 256; ++j) {
            int e = start + j * 256 + t;
            if (e < nE) atomicAdd(&hist[dst[e] >> 8], 1);
        }
        __syncthreads();
        const int c0 = hist[t];
        const int c1 = hist[t + 256];
        s[t] = c0; s[t + 256] = c1;
        __syncthreads();
        // 512-wide inclusive scan with 256 threads
#pragma unroll
        for (int off = 1; off <= 256; off <<= 1) {
            int x0 = (t >= off) ? s[t - off] : 0;
            int x1 = s[t + 256 - off];
            __syncthreads();
            s[t] += x0; s[t + 256] += x1;
            __syncthreads();
        }
        lstart[t]       = s[t] - c0;
        lstart[t + 256] = s[t + 256] - c1;
        curB[t]         = s[t] - c0;
        curB[t + 256]   = s[t + 256] - c1;
        gbase[t]        = c0 ? atomicAdd(&bcursor[t],       c0) : 0;
        gbase[t + 256]  = c1 ? atomicAdd(&bcursor[t + 256], c1) : 0;
        __syncthreads();

#pragma unroll
        for (int j = 0; j < PCHUNK / 256; ++j) {
            int e = start + j * 256 + t;
            if (e < nE) {
                int d  = dst[e];
                int sv = src[e];
                int b  = d >> 8;
                int pos = atomicAdd(&curB[b], 1);
                reorder[pos] = ((unsigned)sv << 8) | ((unsigned)d & 255u);
            }
        }
        __syncthreads();

        // flush: one thread per bucket writes its contiguous run
        for (int b = t; b < NBUCK; b += 256) {
            int st = lstart[b];
            int en = curB[b];
            int gb = gbase[b];
            for (int k = st; k < en; ++k)
                pe[gb + (k - st)] = reorder[k];
        }
    } else {
        // ---------------- layer-0 GEMM ----------------
        const int bid  = blockIdx.x - PGRID;
        const int wv   = t >> 6;
        const int lane = t & 63;
        const int q    = lane >> 4;
        const int m    = lane & 15;
        const int rb   = bid * 64 + wv * 16;
        const int arow = rb + m;
        const bool rok = arow < nrows;
        const float* Ar = A + (size_t)arow * IN_F;

        f32x4 acc[8];
#pragma unroll
        for (int nt = 0; nt < 8; ++nt) acc[nt] = (f32x4){0.f, 0.f, 0.f, 0.f};

#pragma unroll
        for (int kt = 0; kt < 4; ++kt) {
            bf16x8 afr = (bf16x8){0, 0, 0, 0, 0, 0, 0, 0};
            if (rok) {
                float4 v0 = *(const float4*)(Ar + kt * 32 + q * 8);
                float4 v1 = *(const float4*)(Ar + kt * 32 + q * 8 + 4);
                afr[0] = (short)f2bf(v0.x); afr[1] = (short)f2bf(v0.y);
                afr[2] = (short)f2bf(v0.z); afr[3] = (short)f2bf(v0.w);
                afr[4] = (short)f2bf(v1.x); afr[5] = (short)f2bf(v1.y);
                afr[6] = (short)f2bf(v1.z); afr[7] = (short)f2bf(v1.w);
            }
#pragma unroll
            for (int nt = 0; nt < 8; ++nt) {
                bf16x8 bfr = *(const bf16x8*)(Wp + ((size_t)(nt * 4 + kt) * 64 + lane) * 8);
                acc[nt] = __builtin_amdgcn_mfma_f32_16x16x32_bf16(afr, bfr, acc[nt], 0, 0, 0);
            }
        }

        float pel[16], per[16];
#pragma unroll
        for (int i = 0; i < 16; ++i) { pel[i] = 0.f; per[i] = 0.f; }

#pragma unroll
        for (int nt = 0; nt < 8; ++nt) {
            const int col = nt * 16 + m;
            const float alv = al[col];
            const float arv = ar[col];
            const int h = nt >> 1;
#pragma unroll
            for (int reg = 0; reg < 4; ++reg) {
                int row = rb + q * 4 + reg;
                float a = acc[nt][reg];
                if (row < nrows) featb[(size_t)row * 128 + col] = f2bf(a);
                pel[reg * 4 + h] += a * alv;
                per[reg * 4 + h] += a * arv;
            }
        }
#pragma unroll
        for (int sh = 8; sh > 0; sh >>= 1) {
#pragma unroll
            for (int i = 0; i < 16; ++i) {
                pel[i] += __shfl_down(pel[i], sh);
                per[i] += __shfl_down(per[i], sh);
            }
        }
        if (m == 0) {
#pragma unroll
            for (int reg = 0; reg < 4; ++reg) {
                int row = rb + q * 4 + reg;
                if (row < nrows) {
#pragma unroll
                    for (int h = 0; h < 4; ++h) {
                        el[row * 4 + h] = pel[reg * 4 + h];
                        er[row * 4 + h] = per[reg * 4 + h];
                    }
                }
            }
        }
    }
}

// ---------------------------------------------------------------------------
// K3: per-bucket finalize — degree histogram + local scan -> rowptr/deg,
// within-bucket sort -> sorted_boff (BYTE offsets src*256, = ed & ~255).
// ---------------------------------------------------------------------------
__global__ __launch_bounds__(256) void bucket_finalize(const unsigned int* __restrict__ pe,
                                                       const int* __restrict__ bcursor,
                                                       int* __restrict__ rowptr,
                                                       int* __restrict__ deg,
                                                       int* __restrict__ sorted_boff) {
    __shared__ int deg_l[256];
    __shared__ int s[256];
    __shared__ int cur[256];

    const int b  = blockIdx.x;
    const int t  = threadIdx.x;
    const int base = b * BCAP;
    const int cnt  = bcursor[b] - base;
    const int n    = b * 256 + t;

    deg_l[t] = 0;
    __syncthreads();
    for (int i = t; i < cnt; i += 256)
        atomicAdd(&deg_l[pe[base + i] & 255u], 1);
    __syncthreads();

    const int dv = deg_l[t];
    s[t] = dv;
    __syncthreads();
#pragma unroll
    for (int off = 1; off < 256; off <<= 1) {
        int x = (t >= off) ? s[t - off] : 0;
        __syncthreads();
        s[t] += x;
        __syncthreads();
    }
    const int off_l = s[t] - dv;
    if (n < N_NODES) {
        rowptr[n] = base + off_l;
        deg[n]    = dv;
    }
    cur[t] = off_l;
    __syncthreads();

    for (int i = t; i < cnt; i += 256) {
        unsigned int ed = pe[base + i];
        int pos = atomicAdd(&cur[ed & 255u], 1);
        sorted_boff[base + pos] = (int)(ed & 0xFFFFFF00u);   // src*256 byte offset
    }
}

// ---------------------------------------------------------------------------
// MFMA GEMM, bf16 A (layer 1): featb = Ab @ Wp, el/er fused. Barrier-free.
// ---------------------------------------------------------------------------
__global__ __launch_bounds__(256) void gemm128_mfma_bf16(const unsigned short* __restrict__ Ab,
                                                         const unsigned short* __restrict__ Wp,
                                                         const float* __restrict__ al,
                                                         const float* __restrict__ ar,
                                                         unsigned short* __restrict__ featb,
                                                         float* __restrict__ el,
                                                         float* __restrict__ er,
                                                         int nrows) {
    const int t    = threadIdx.x;
    const int wv   = t >> 6;
    const int lane = t & 63;
    const int q    = lane >> 4;
    const int m    = lane & 15;
    const int rb   = blockIdx.x * 64 + wv * 16;
    const int arow = rb + m;
    const bool rok = arow < nrows;
    const unsigned short* Ar = Ab + (size_t)arow * IN_F;

    f32x4 acc[8];
#pragma unroll
    for (int nt = 0; nt < 8; ++nt) acc[nt] = (f32x4){0.f, 0.f, 0.f, 0.f};

#pragma unroll
    for (int kt = 0; kt < 4; ++kt) {
        bf16x8 afr = (bf16x8){0, 0, 0, 0, 0, 0, 0, 0};
        if (rok) afr = *(const bf16x8*)(Ar + kt * 32 + q * 8);
#pragma unroll
        for (int nt = 0; nt < 8; ++nt) {
            bf16x8 bfr = *(const bf16x8*)(Wp + ((size_t)(nt * 4 + kt) * 64 + lane) * 8);
            acc[nt] = __builtin_amdgcn_mfma_f32_16x16x32_bf16(afr, bfr, acc[nt], 0, 0, 0);
        }
    }

    float pel[16], per[16];
#pragma unroll
    for (int i = 0; i < 16; ++i) { pel[i] = 0.f; per[i] = 0.f; }

#pragma unroll
    for (int nt = 0; nt < 8; ++nt) {
        const int col = nt * 16 + m;
        const float alv = al[col];
        const float arv = ar[col];
        const int h = nt >> 1;
#pragma unroll
        for (int reg = 0; reg < 4; ++reg) {
            int row = rb + q * 4 + reg;
            float a = acc[nt][reg];
            if (row < nrows) featb[(size_t)row * 128 + col] = f2bf(a);
            pel[reg * 4 + h] += a * alv;
            per[reg * 4 + h] += a * arv;
        }
    }
#pragma unroll
    for (int sh = 8; sh > 0; sh >>= 1) {
#pragma unroll
        for (int i = 0; i < 16; ++i) {
            pel[i] += __shfl_down(pel[i], sh);
            per[i] += __shfl_down(per[i], sh);
        }
    }
    if (m == 0) {
#pragma unroll
        for (int reg = 0; reg < 4; ++reg) {
            int row = rb + q * 4 + reg;
            if (row < nrows) {
#pragma unroll
                for (int h = 0; h < 4; ++h) {
                    el[row * 4 + h] = pel[reg * 4 + h];
                    er[row * 4 + h] = per[reg * 4 + h];
                }
            }
        }
    }
}

// ---------------------------------------------------------------------------
// MFMA dual GEMM layer 2 (bf16 A): [feat2b(bf16) | res2(f32)] = A @ [W2|resW2].
// ---------------------------------------------------------------------------
__global__ __launch_bounds__(256) void gemm16_mfma(const unsigned short* __restrict__ Ab,
                                                   const unsigned short* __restrict__ Wp,
                                                   const float* __restrict__ al,
                                                   const float* __restrict__ ar,
                                                   unsigned short* __restrict__ feat2b,
                                                   float* __restrict__ res2,
                                                   float* __restrict__ el,
                                                   float* __restrict__ er,
                                                   int nrows) {
    const int t    = threadIdx.x;
    const int wv   = t >> 6;
    const int lane = t & 63;
    const int q    = lane >> 4;
    const int m    = lane & 15;
    const int rb   = blockIdx.x * 64 + wv * 16;
    const int arow = rb + m;
    const bool rok = arow < nrows;
    const unsigned short* Ar = Ab + (size_t)arow * IN_F;

    f32x4 acc0 = (f32x4){0.f, 0.f, 0.f, 0.f};
    f32x4 acc1 = (f32x4){0.f, 0.f, 0.f, 0.f};

#pragma unroll
    for (int kt = 0; kt < 4; ++kt) {
        bf16x8 afr = (bf16x8){0, 0, 0, 0, 0, 0, 0, 0};
        if (rok) afr = *(const bf16x8*)(Ar + kt * 32 + q * 8);
        bf16x8 b0 = *(const bf16x8*)(Wp + ((size_t)(0 * 4 + kt) * 64 + lane) * 8);
        bf16x8 b1 = *(const bf16x8*)(Wp + ((size_t)(1 * 4 + kt) * 64 + lane) * 8);
        acc0 = __builtin_amdgcn_mfma_f32_16x16x32_bf16(afr, b0, acc0, 0, 0, 0);
        acc1 = __builtin_amdgcn_mfma_f32_16x16x32_bf16(afr, b1, acc1, 0, 0, 0);
    }

    float pel[4], per[4];
    const float alv = al[m];
    const float arv = ar[m];
#pragma unroll
    for (int reg = 0; reg < 4; ++reg) {
        int row = rb + q * 4 + reg;
        float a = acc0[reg];
        if (row < nrows) {
            feat2b[(size_t)row * 16 + m] = f2bf(a);
            res2[(size_t)row * 16 + m]   = acc1[reg];
        }
        pel[reg] = a * alv;
        per[reg] = a * arv;
    }
#pragma unroll
    for (int sh = 8; sh > 0; sh >>= 1) {
#pragma unroll
        for (int reg = 0; reg < 4; ++reg) {
            pel[reg] += __shfl_down(pel[reg], sh);
            per[reg] += __shfl_down(per[reg], sh);
        }
    }
    if (m == 0) {
#pragma unroll
        for (int reg = 0; reg < 4; ++reg) {
            int row = rb + q * 4 + reg;
            if (row < nrows) { el[row] = pel[reg]; er[row] = per[reg]; }
        }
    }
}

// ---------------------------------------------------------------------------
// Pull aggregation, H=4, D=32, bf16 gathers, wave per node, bf16 in/out.
// Terminal form: delivered bytes (~470 MB/dispatch) at the device's ~6.3 TB/s
// ceiling; FETCH at the compulsory 8-XCD floor (241 MB); fp8 blocked by
// precision (v8/v9); 6 scheduling/locality variants all neutral-or-worse.
// ---------------------------------------------------------------------------
__global__ __launch_bounds__(256) void gat_agg128(const int* __restrict__ rowptr,
                                                  const int* __restrict__ deg,
                                                  const int* __restrict__ sorted_boff,
                                                  const float* __restrict__ el,
                                                  const float* __restrict__ er,
                                                  const unsigned short* __restrict__ featb,
                                                  const unsigned short* __restrict__ resb,
                                                  unsigned short* __restrict__ outb) {
    __shared__ __align__(16) int   sS[4][64];
    __shared__ __align__(16) float sW[4][4][68];

    const int wv   = threadIdx.x >> 6;
    const int lane = threadIdx.x & 63;
    const int nd   = blockIdx.x * 4 + wv;

    const int dg = deg[nd];
    const int r0 = rowptr[nd];
    const int h  = lane >> 4;
    const unsigned int lane4 = (unsigned int)(lane << 2);
    const float4 er4 = *(const float4*)(er + nd * 4);
    const char* fb = (const char*)featb;
    const char* eb = (const char*)el;

    float dx = 0.f, dy = 0.f, dz = 0.f, dw = 0.f;
    float ax = 0.f, ay = 0.f;

    for (int base = 0; base < dg; base += 64) {
        int m = dg - base; if (m > 64) m = 64;

        // ---- stage: each lane owns one edge ----
        int boff = 0;
        float4 w4 = {0.f, 0.f, 0.f, 0.f};
        if (lane < m) {
            boff = sorted_boff[r0 + base + lane];
            float4 e4 = *(const float4*)(eb + (unsigned int)(boff >> 4));
            float t_;
            t_ = e4.x + er4.x; t_ = t_ > 0.f ? t_ : NEG_SLOPE * t_; w4.x = __expf(t_);
            t_ = e4.y + er4.y; t_ = t_ > 0.f ? t_ : NEG_SLOPE * t_; w4.y = __expf(t_);
            t_ = e4.z + er4.z; t_ = t_ > 0.f ? t_ : NEG_SLOPE * t_; w4.z = __expf(t_);
            t_ = e4.w + er4.w; t_ = t_ > 0.f ? t_ : NEG_SLOPE * t_; w4.w = __expf(t_);
        }
        // wave-synchronous: same wave writes and reads its slice
        sS[wv][lane]    = boff;
        sW[wv][0][lane] = w4.x;
        sW[wv][1][lane] = w4.y;
        sW[wv][2][lane] = w4.z;
        sW[wv][3][lane] = w4.w;
        dx += w4.x; dy += w4.y; dz += w4.z; dw += w4.w;

        // ---- consume: 8 edges per group, no conditionals ----
        const int mr = (m + 7) & ~7;
        for (int i = 0; i < mr; i += 8) {
            const int4   sa = *(const int4*)(&sS[wv][i]);
            const int4   sb = *(const int4*)(&sS[wv][i + 4]);
            const float4 wa = *(const float4*)(&sW[wv][h][i]);
            const float4 wb = *(const float4*)(&sW[wv][h][i + 4]);

            unsigned int u0 = ld_u32(fb, (unsigned int)sa.x + lane4);
            unsigned int u1 = ld_u32(fb, (unsigned int)sa.y + lane4);
            unsigned int u2 = ld_u32(fb, (unsigned int)sa.z + lane4);
            unsigned int u3 = ld_u32(fb, (unsigned int)sa.w + lane4);
            unsigned int u4 = ld_u32(fb, (unsigned int)sb.x + lane4);
            unsigned int u5 = ld_u32(fb, (unsigned int)sb.y + lane4);
            unsigned int u6 = ld_u32(fb, (unsigned int)sb.z + lane4);
            unsigned int u7 = ld_u32(fb, (unsigned int)sb.w + lane4);

            ax += wa.x * __uint_as_float(u0 << 16);
            ay += wa.x * __uint_as_float(u0 & 0xFFFF0000u);
            ax += wa.y * __uint_as_float(u1 << 16);
            ay += wa.y * __uint_as_float(u1 & 0xFFFF0000u);
            ax += wa.z * __uint_as_float(u2 << 16);
            ay += wa.z * __uint_as_float(u2 & 0xFFFF0000u);
            ax += wa.w * __uint_as_float(u3 << 16);
            ay += wa.w * __uint_as_float(u3 & 0xFFFF0000u);
            ax += wb.x * __uint_as_float(u4 << 16);
            ay += wb.x * __uint_as_float(u4 & 0xFFFF0000u);
            ax += wb.y * __uint_as_float(u5 << 16);
            ay += wb.y * __uint_as_float(u5 & 0xFFFF0000u);
            ax += wb.z * __uint_as_float(u6 << 16);
            ay += wb.z * __uint_as_float(u6 & 0xFFFF0000u);
            ax += wb.w * __uint_as_float(u7 << 16);
            ay += wb.w * __uint_as_float(u7 & 0xFFFF0000u);
        }
    }

    // den: butterfly-reduce the staged weight sums across all 64 lanes
#pragma unroll
    for (int sh = 1; sh < 64; sh <<= 1) {
        dx += __shfl_xor(dx, sh);
        dy += __shfl_xor(dy, sh);
        dz += __shfl_xor(dz, sh);
        dw += __shfl_xor(dw, sh);
    }
    float den = (h == 0) ? dx : (h == 1) ? dy : (h == 2) ? dz : dw;

    float scale = den > 0.f ? 1.f / den : 0.f;
    float ox = ax * scale, oy = ay * scale;
    size_t o0 = (size_t)nd * 128 + lane * 2;
    if (resb) {
        ushort2 rv = *(const ushort2*)(resb + o0);
        ox += bf2f(rv.x);
        oy += bf2f(rv.y);
    }
    ox = fmaxf(ox, 0.f);
    oy = fmaxf(oy, 0.f);
    ushort2 ou;
    ou.x = f2bf(ox);
    ou.y = f2bf(oy);
    *(ushort2*)(outb + o0) = ou;
}

// ---------------------------------------------------------------------------
// Pull aggregation, H=1, C=16: wave per node, LDS staging, 8 edge-groups of
// 8 lanes; lane owns a feature pair. Final output f32 (+res2).
// sorted_boff holds src*256; feat2b byte = boff>>3, el byte = boff>>6.
// ---------------------------------------------------------------------------
__global__ __launch_bounds__(256) void gat_agg16(const int* __restrict__ rowptr,
                                                 const int* __restrict__ deg,
                                                 const int* __restrict__ sorted_boff,
                                                 const float* __restrict__ el,
                                                 const float* __restrict__ er,
                                                 const unsigned short* __restrict__ feat2b,
                                                 const float* __restrict__ res,
                                                 float* __restrict__ out) {
    __shared__ int   sS[4][64];
    __shared__ float sW[4][64];

    const int wv   = threadIdx.x >> 6;
    const int lane = threadIdx.x & 63;
    const int nd   = blockIdx.x * 4 + (threadIdx.x >> 6);
    const int g    = lane >> 3;
    const unsigned int flane4 = (unsigned int)((lane & 7) << 2);
    const char* f2base = (const char*)feat2b;
    const char* eb = (const char*)el;

    const int dg = deg[nd];
    const int r0 = rowptr[nd];
    const float erd = er[nd];

    float ax = 0.f, ay = 0.f, den = 0.f;

    for (int base = 0; base < dg; base += 64) {
        int m = dg - base; if (m > 64) m = 64;
        if (lane < m) {
            int boff = sorted_boff[r0 + base + lane];
            sS[wv][lane] = boff;
            float v = *(const float*)(eb + (unsigned int)(boff >> 6)) + erd;
            v = v > 0.f ? v : NEG_SLOPE * v;
            sW[wv][lane] = __expf(v);
        }
        for (int i = g; i < m; i += 8) {
            int bo  = sS[wv][i];
            float w = sW[wv][i];
            den += w;
            unsigned int u = *(const unsigned int*)(f2base + (unsigned int)(bo >> 3) + flane4);
            ax += w * __uint_as_float(u << 16);
            ay += w * __uint_as_float(u & 0xFFFF0000u);
        }
    }

    ax += __shfl_down(ax, 32); ay += __shfl_down(ay, 32); den += __shfl_down(den, 32);
    ax += __shfl_down(ax, 16); ay += __shfl_down(ay, 16); den += __shfl_down(den, 16);
    ax += __shfl_down(ax, 8);  ay += __shfl_down(ay, 8);  den += __shfl_down(den, 8);

    if (lane < 8) {
        float scale = den > 0.f ? 1.f / den : 0.f;
        size_t o0 = (size_t)nd * 16 + ((lane & 7) << 1);
        float2 o;
        o.x = ax * scale + res[o0];
        o.y = ay * scale + res[o0 + 1];
        *(float2*)(out + o0) = o;
    }
}

// ---------------------------------------------------------------------------
extern "C" void kernel_launch(void* const* d_in, const int* in_sizes, int n_in,
                              void* d_out, int out_size, void* d_ws, size_t ws_size,
                              hipStream_t stream) {
    const float* inputs = (const float*)d_in[0];
    const int*   src    = (const int*)d_in[1];
    const int*   dst    = (const int*)d_in[2];
    const float* W0     = (const float*)d_in[3];
    const float* al0    = (const float*)d_in[4];
    const float* ar0    = (const float*)d_in[5];
    const float* W1     = (const float*)d_in[6];
    const float* al1    = (const float*)d_in[7];
    const float* ar1    = (const float*)d_in[8];
    const float* W2     = (const float*)d_in[9];
    const float* al2    = (const float*)d_in[10];
    const float* ar2    = (const float*)d_in[11];
    const float* resW2  = (const float*)d_in[12];
    float* out = (float*)d_out;

    const size_t NF = (size_t)N_NODES * 128;
    float* ws   = (float*)d_ws;
    float* el   = ws;                                  // N*4
    float* er   = el + (size_t)N_NODES * 4;            // N*4
    float* res2 = er + (size_t)N_NODES * 4;            // N*16
    unsigned short* hbufb  = (unsigned short*)(res2 + (size_t)N_NODES * 16);  // N*128 bf16
    unsigned short* featb  = hbufb + NF;               // N*128 bf16
    unsigned short* feat2b = featb + NF;               // N*16 bf16
    unsigned short* W0p    = feat2b + (size_t)N_NODES * 16;  // 16384
    unsigned short* W1p    = W0p + 16384;                    // 16384
    unsigned short* W2p    = W1p + 16384;                    // 8192
    int* iws = (int*)(W2p + 8192);
    unsigned int* pe = (unsigned int*)iws;             // NBUCK*BCAP padded
    int* sorted_boff = iws + NBUCK * BCAP;             // NBUCK*BCAP padded
    int* deg         = sorted_boff + NBUCK * BCAP;     // N
    int* rowptr      = deg + N_NODES;                  // N
    int* bcursor     = rowptr + N_NODES;               // 512

    dim3 blk(256);
    int aggGrid = N_NODES / 4;                         // 25000

    // ---- K1: cursor init + weight pack ----
    init_pack<<<162, blk, 0, stream>>>(bcursor, W0, W1, W2, resW2, W0p, W1p, W2p);
    // ---- K2: partition + layer-0 GEMM ----
    part_gemm0<<<PGRID + GEMMGRID, blk, 0, stream>>>(src, dst, bcursor, pe, N_EDGES,
                                                     inputs, W0p, al0, ar0, featb,
                                                     el, er, N_NODES);
    // ---- K3: finalize CSR ----
    bucket_finalize<<<PGRID, blk, 0, stream>>>(pe, bcursor, rowptr, deg, sorted_boff);

    // ---- layer 0 aggregation ----
    gat_agg128<<<aggGrid, blk, 0, stream>>>(rowptr, deg, sorted_boff, el, er, featb,
                                            nullptr, hbufb);

    // ---- layer 1 ----
    gemm128_mfma_bf16<<<GEMMGRID, blk, 0, stream>>>(hbufb, W1p, al1, ar1, featb,
                                                    el, er, N_NODES);
    gat_agg128<<<aggGrid, blk, 0, stream>>>(rowptr, deg, sorted_boff, el, er, featb,
                                            hbufb, hbufb);

    // ---- layer 2 ----
    gemm16_mfma<<<GEMMGRID, blk, 0, stream>>>(hbufb, W2p, al2, ar2, feat2b, res2,
                                              el, er, N_NODES);
    gat_agg16<<<aggGrid, blk, 0, stream>>>(rowptr, deg, sorted_boff, el, er, feat2b,
                                           res2, out);
}